// Round 7
// baseline (6856.893 us; speedup 1.0000x reference)
//
#include <hip/hip_runtime.h>
#include <math.h>
#include <stdint.h>

namespace {

constexpr int NROW = 16384;   // B*A
constexpr int NF   = 512;     // n_in
constexpr int MIND = 2048;    // inducing points
constexpr float CC = 0.98f;   // centering constant: Kx = exp(-d), d ~ 0.004
constexpr int GJ_BLOCKS = 512;  // 2 blocks/CU — co-residency with 2x margin

typedef _Float16 half8 __attribute__((ext_vector_type(8)));
typedef _Float16 half4v __attribute__((ext_vector_type(4)));
typedef float floatx4 __attribute__((ext_vector_type(4)));

__device__ __forceinline__ void gload16(const void* g, void* l) {
  __builtin_amdgcn_global_load_lds(
      (__attribute__((address_space(1))) void*)g,
      (__attribute__((address_space(3))) void*)l, 16, 0, 0);
}

#define MEMFENCE asm volatile("" ::: "memory")
#define GATE(N) asm volatile("s_waitcnt vmcnt(" #N ")" ::: "memory")

// ---- manual grid barrier (sense-reversing, agent-scope atomics) ----------
// Blocks all co-resident by construction (512 blocks, 2/CU, 2x resource
// margin).  cnt/gen live in memset-zeroed workspace -> reset every launch.
__device__ __forceinline__ void gbar(int* cnt, int* gen, int nb) {
  __syncthreads();
  if (threadIdx.x == 0) {
    __threadfence();   // release prior writes (agent scope)
    const int g = __hip_atomic_load(gen, __ATOMIC_RELAXED,
                                    __HIP_MEMORY_SCOPE_AGENT);
    if (__hip_atomic_fetch_add(cnt, 1, __ATOMIC_ACQ_REL,
                               __HIP_MEMORY_SCOPE_AGENT) == nb - 1) {
      __hip_atomic_store(cnt, 0, __ATOMIC_RELAXED, __HIP_MEMORY_SCOPE_AGENT);
      __hip_atomic_fetch_add(gen, 1, __ATOMIC_RELEASE,
                             __HIP_MEMORY_SCOPE_AGENT);
    } else {
      while (__hip_atomic_load(gen, __ATOMIC_ACQUIRE,
                               __HIP_MEMORY_SCOPE_AGENT) == g)
        __builtin_amdgcn_s_sleep(16);
    }
    __threadfence();   // acquire side before subsequent reads
  }
  __syncthreads();
}

// ---------------------------------------------------------------- stats ----
__global__ __launch_bounds__(256) void stats_kernel(
    const float* __restrict__ x, const int* __restrict__ mask,
    float* __restrict__ sum, float* __restrict__ sumsq, float* __restrict__ cnt)
{
  const int t = threadIdx.x;
  const int row0 = blockIdx.x * 64;
  float s0 = 0.f, s1 = 0.f, q0 = 0.f, q1 = 0.f, c = 0.f;
  for (int r = 0; r < 64; ++r) {
    const int row = row0 + r;
    const float m = (mask[row] != 0) ? 1.f : 0.f;
    const float v0 = x[(size_t)row * NF + t];
    const float v1 = x[(size_t)row * NF + t + 256];
    s0 += m * v0; q0 += m * v0 * v0;
    s1 += m * v1; q1 += m * v1 * v1;
    c += m;
  }
  atomicAdd(&sum[t], s0);        atomicAdd(&sum[t + 256], s1);
  atomicAdd(&sumsq[t], q0);      atomicAdd(&sumsq[t + 256], q1);
  if (t == 0) atomicAdd(cnt, c);
}

__global__ __launch_bounds__(256) void finalize_stats(
    const float* __restrict__ sum, const float* __restrict__ sumsq,
    const float* __restrict__ cnt, const float* __restrict__ gamma,
    float* __restrict__ meanv, float* __restrict__ stdv,
    float* __restrict__ zsv, float* __restrict__ giv)
{
  const int f = blockIdx.x * 256 + threadIdx.x;   // <<<2,256>>>
  const float n = cnt[0];
  const float mu = sum[f] / n;
  const float var = (sumsq[f] - sum[f] * mu) / (n - 1.0f);
  const float sd = sqrtf(var) + 1e-5f;
  const float g = gamma[f];
  const float g2 = g * g + 0.001f;
  meanv[f] = mu;
  stdv[f]  = sd;
  zsv[f]   = 1.0f / (sd * g2);
  giv[f]   = 1.0f / g2;
}

// z rows (masked, normalized, /g2) fp16 + zi rows fp16 + fp32 norms of the
// fp16-ROUNDED values (so d_jj ~ 0 exactly)
__global__ __launch_bounds__(256) void make_z(
    const float* __restrict__ x, const int* __restrict__ mask,
    const float* __restrict__ ip, const float* __restrict__ meanv,
    const float* __restrict__ zsv, const float* __restrict__ giv,
    _Float16* __restrict__ Zh, _Float16* __restrict__ Zih,
    float* __restrict__ rnorm, float* __restrict__ cnorm)
{
  const int row = blockIdx.x;
  const int t = threadIdx.x;
  float v0, v1;
  if (row < NROW) {
    const float m = (mask[row] != 0) ? 1.f : 0.f;
    v0 = (x[(size_t)row * NF + t      ] - meanv[t      ]) * zsv[t      ] * m;
    v1 = (x[(size_t)row * NF + t + 256] - meanv[t + 256]) * zsv[t + 256] * m;
    const _Float16 h0 = (_Float16)v0, h1 = (_Float16)v1;
    Zh[(size_t)row * NF + t] = h0;
    Zh[(size_t)row * NF + t + 256] = h1;
    v0 = (float)h0; v1 = (float)h1;
  } else {
    const int r = row - NROW;
    v0 = ip[(size_t)r * NF + t      ] * giv[t      ];
    v1 = ip[(size_t)r * NF + t + 256] * giv[t + 256];
    const _Float16 h0 = (_Float16)v0, h1 = (_Float16)v1;
    Zih[(size_t)r * NF + t] = h0;
    Zih[(size_t)r * NF + t + 256] = h1;
    v0 = (float)h0; v1 = (float)h1;
  }
  float nrm = v0 * v0 + v1 * v1;
  #pragma unroll
  for (int off = 32; off; off >>= 1) nrm += __shfl_xor(nrm, off);
  __shared__ float red[4];
  if ((t & 63) == 0) red[t >> 6] = nrm;
  __syncthreads();
  if (t == 0) {
    const float s = red[0] + red[1] + red[2] + red[3];
    if (row < NROW) rnorm[row] = s; else cnorm[row - NROW] = s;
  }
}

// ------------------------------------------------- 256x256 deep-pipe GEMM --
// (R5 proven version, unchanged: fused-by-concatenation, XCD swizzle,
//  LDS slot-swizzle, counted vmcnt(8) 4-buffer pipeline.)
template <int PASS>
__global__ __launch_bounds__(512, 2) void mfma_gemm256f(
    const _Float16* __restrict__ A, const _Float16* __restrict__ B, int K,
    const float* __restrict__ rn, const float* __restrict__ cn,
    _Float16* __restrict__ DKout, float* __restrict__ Cf,
    const _Float16* __restrict__ DK, const float* __restrict__ u,
    float* __restrict__ varacc,
    const float* __restrict__ colsumR, const float* __restrict__ stdv,
    const float* __restrict__ meanv, const int* __restrict__ mask)
{
  __shared__ __align__(16) _Float16 Asmem[4][256 * 32];
  __shared__ __align__(16) _Float16 Bsmem[4][256 * 32];

  const int tid = threadIdx.x;
  const int w = tid >> 6, L = tid & 63;
  const int wm = w >> 2, wn = w & 3;          // 2 x 4 waves
  const int lq = L >> 4, lr = L & 15;
  // ---- XCD-aware remap (T1): same-bm blocks contiguous on one XCD ----
  int bn, bm;
  if constexpr (PASS == 0) {
    const int wgid = blockIdx.y * 8 + blockIdx.x;    // grid (8,72)
    const int xcd = wgid & 7, q = wgid >> 3;         // q: 0..71
    bm = xcd + 8 * (q >> 3);                         // 0..71, bijective
    bn = q & 7;                                      // 0..7
  } else {
    const int wgid = blockIdx.y * 10 + blockIdx.x;   // grid (10,64)
    const int xcd = wgid & 7, q = wgid >> 3;         // q: 0..79
    bm = xcd + 8 * (q / 10);                         // 0..63, bijective
    bn = q % 10;                                     // 0..9
  }
  const int NT = K >> 5;                      // K tiles of 32

  // ---- staging maps (linear LDS dest = base + lane*16; swizzled global src)
  const int srow  = tid >> 2;                 // 0..127 (chunk j adds 128)
  const int sslot = tid & 3;                  // LDS 16B slot within 64B row
  const int gslot = sslot ^ ((tid >> 3) & 3); // swizzled source slot
  const _Float16* Ag = A + (size_t)(bm * 256 + srow) * K + gslot * 8;
  const _Float16* Bg = B + (size_t)(bn * 256 + srow) * K + gslot * 8;
  const size_t rstride = (size_t)128 * K;
  const int ldst = srow * 32 + sslot * 8;     // halves

  // ---- fragment read offsets (swizzled): slot = lq ^ ((lr>>1)&3)
  const int fswz = (lq ^ ((lr >> 1) & 3)) * 8;
  const int aoff = (wm * 128 + lr) * 32 + fswz;
  const int boff = (wn * 64  + lr) * 32 + fswz;

  floatx4 acc[8][4] = {};

  auto stageA = [&](int t) {
    _Float16* dst = Asmem[t & 3] + ldst;
    const _Float16* src = Ag + (size_t)t * 32;
    gload16(src, dst);
    gload16(src + rstride, dst + 128 * 32);
  };
  auto stageB = [&](int t) {
    _Float16* dst = Bsmem[t & 3] + ldst;
    const _Float16* src = Bg + (size_t)t * 32;
    gload16(src, dst);
    gload16(src + rstride, dst + 128 * 32);
  };

  // ---- prologue: stage tiles 0,1,2 (12 loads); gate tile 0 with vmcnt(8)
  stageA(0); stageB(0);
  if (NT > 1) { stageA(1); stageB(1); }
  if (NT > 2) { stageA(2); stageB(2); }
  if (NT > 2)      { GATE(8); }
  else if (NT > 1) { GATE(4); }
  else             { GATE(0); }
  __builtin_amdgcn_s_barrier();
  MEMFENCE;

  for (int t = 0; t < NT; ++t) {
    const _Float16* As = Asmem[t & 3];
    const _Float16* Bs = Bsmem[t & 3];
    half8 af[4], bf[4], af2[4];

    // ---- phase 0: quadrant mi0-3 --------------------------------------
    #pragma unroll
    for (int mi = 0; mi < 4; ++mi) af[mi] = *(const half8*)&As[aoff + mi * 512];
    #pragma unroll
    for (int ni = 0; ni < 4; ++ni) bf[ni] = *(const half8*)&Bs[boff + ni * 512];
    if (t + 3 < NT) stageA(t + 3);
    MEMFENCE;
    __builtin_amdgcn_s_barrier();
    MEMFENCE;
    __builtin_amdgcn_s_setprio(1);
    #pragma unroll
    for (int mi = 0; mi < 4; ++mi)
      #pragma unroll
      for (int ni = 0; ni < 4; ++ni)
        acc[mi][ni] = __builtin_amdgcn_mfma_f32_16x16x32_f16(
            af[mi], bf[ni], acc[mi][ni], 0, 0, 0);
    __builtin_amdgcn_s_setprio(0);

    // ---- phase 1: quadrant mi4-7 + counted-vmcnt gate for tile t+1 ----
    #pragma unroll
    for (int mi = 0; mi < 4; ++mi)
      af2[mi] = *(const half8*)&As[aoff + (mi + 4) * 512];
    if (t + 3 < NT) stageB(t + 3);
    // outstanding after this phase's stages: tiles {t+2 .. min(t+3,NT-1)}
    if (t + 4 <= NT)      { GATE(8); }   // 2 future tiles in flight
    else if (t + 3 == NT) { GATE(4); }   // 1 future tile
    else if (t + 2 == NT) { GATE(0); }   // drain before last tile
    __builtin_amdgcn_s_barrier();
    MEMFENCE;
    __builtin_amdgcn_s_setprio(1);
    #pragma unroll
    for (int mi = 0; mi < 4; ++mi)
      #pragma unroll
      for (int ni = 0; ni < 4; ++ni)
        acc[mi + 4][ni] = __builtin_amdgcn_mfma_f32_16x16x32_f16(
            af2[mi], bf[ni], acc[mi + 4][ni], 0, 0, 0);
    __builtin_amdgcn_s_setprio(0);
  }

  // ---- epilogue.  C/D layout: col = lane&15, row = (lane>>4)*4 + reg
  const int grb = bm * 256 + wm * 128;
  const int gcb = bn * 256 + wn * 64;

  if constexpr (PASS == 0) {
    if (bm < NROW / 256) {             // EPI0: Kx -> DK fp16
      #pragma unroll
      for (int mi = 0; mi < 8; ++mi)
        #pragma unroll
        for (int e = 0; e < 4; ++e) {
          const int gr = grb + mi * 16 + lq * 4 + e;
          const float rni = rn[gr];
          #pragma unroll
          for (int ni = 0; ni < 4; ++ni) {
            const int gc = gcb + ni * 16 + lr;
            const float d = rni + cn[gc] - 2.f * acc[mi][ni][e];
            DKout[(size_t)gr * MIND + gc] = (_Float16)(expf(-fabsf(d)) - CC);
          }
        }
    } else {                           // EPI1: Kreg fp32 (+0.05 I)
      #pragma unroll
      for (int mi = 0; mi < 8; ++mi)
        #pragma unroll
        for (int e = 0; e < 4; ++e) {
          const int gr = grb + mi * 16 + lq * 4 + e;
          const int gr2 = gr - NROW;
          const float rni = rn[gr];    // rn = rnorm||cnorm contiguous
          #pragma unroll
          for (int ni = 0; ni < 4; ++ni) {
            const int gc = gcb + ni * 16 + lr;
            const float d = rni + cn[gc] - 2.f * acc[mi][ni][e];
            float kx = expf(-fabsf(d));
            if (gr2 == gc) kx += 0.05f;
            Cf[(size_t)gr2 * MIND + gc] = kx;
          }
        }
    }
  } else {
    if (bn < MIND / 256) {             // EPI2: var reduction
      #pragma unroll
      for (int mi = 0; mi < 8; ++mi)
        #pragma unroll
        for (int e = 0; e < 4; ++e) {
          const int gr = grb + mi * 16 + lq * 4 + e;
          float partial = 0.f;
          #pragma unroll
          for (int ni = 0; ni < 4; ++ni) {
            const int gc = gcb + ni * 16 + lr;
            const float tv = acc[mi][ni][e] + CC * u[gc];
            partial += tv * (CC + (float)DK[(size_t)gr * MIND + gc]);
          }
          partial += __shfl_xor(partial, 1);
          partial += __shfl_xor(partial, 2);
          partial += __shfl_xor(partial, 4);
          partial += __shfl_xor(partial, 8);
          if (lr == 0) atomicAdd(&varacc[gr], partial);
        }
    } else {                           // EPI3: x_new
      const int gcb3 = (bn - MIND / 256) * 256 + wn * 64;
      #pragma unroll
      for (int mi = 0; mi < 8; ++mi)
        #pragma unroll
        for (int e = 0; e < 4; ++e) {
          const int gr = grb + mi * 16 + lq * 4 + e;
          const float mrow = (mask[gr] != 0) ? 1.f : 0.f;
          #pragma unroll
          for (int ni = 0; ni < 4; ++ni) {
            const int gc3 = gcb3 + ni * 16 + lr;
            const float v = acc[mi][ni][e] + CC * colsumR[gc3];
            Cf[(size_t)gr * NF + gc3] = (v * stdv[gc3] + meanv[gc3]) * mrow;
          }
        }
    }
  }
}

// ========== fused Gauss-Jordan + post (single launch, manual grid bar) =====
// Math bodies verbatim from the proven R1/R5 launch-based trio; gbar()
// placed exactly where launch boundaries were.

__device__ __forceinline__ void d_gj_diag(
    float* __restrict__ A, float* __restrict__ Pall, int k, float* S1)
{
  const int o = k * 64;
  const int t = threadIdx.x;
  #define D(r, c) S1[(r) * 68 + (c)]
  #pragma unroll
  for (int l = 0; l < 4; ++l) {
    const int v = t + l * 256;
    const int r = v >> 4, c4 = (v & 15) << 2;
    *(float4*)&D(r, c4) = *(const float4*)(A + (size_t)(o + r) * MIND + o + c4);
  }
  __syncthreads();
  const int i = t >> 2, c0 = (t & 3) * 16;
  for (int s = 0; s < 64; ++s) {
    const float p = 1.0f / D(s, s);
    if (t < 64 && t != s) D(s, t) *= p;
    __syncthreads();
    if (i != s) {
      const float f = D(i, s);
      #pragma unroll
      for (int c = c0; c < c0 + 16; c += 4) {
        float4 ds = *(const float4*)&D(s, c);
        float4 di = *(const float4*)&D(i, c);
        di.x -= f * ds.x; di.y -= f * ds.y; di.z -= f * ds.z; di.w -= f * ds.w;
        *(float4*)&D(i, c) = di;
      }
      if (s >= c0 && s < c0 + 16) D(i, s) = -f * p;
    }
    if (t == 0) D(s, s) = p;
    __syncthreads();
  }
  float* P = Pall + k * 4096;
  #pragma unroll
  for (int l = 0; l < 4; ++l) {
    const int v = t + l * 256;
    const int r = v >> 4, c4 = (v & 15) << 2;
    const float4 dv = *(const float4*)&D(r, c4);
    *(float4*)(P + r * 64 + c4) = dv;
    *(float4*)(A + (size_t)(o + r) * MIND + o + c4) = dv;
  }
  #undef D
}

// b<32: CP_i = A[i][o]*P (skip i==o); b>=32: Bsave row-panel copy
__device__ __forceinline__ void d_gj_prep(
    float* __restrict__ A, float* __restrict__ Pall,
    float* __restrict__ CP, float* __restrict__ Bsave, int k, int b,
    float* S1, float* S2)
{
  const int o = k * 64;
  const int t = threadIdx.x;
  if (b >= 32) {
    const int j0 = (b - 32) * 64;
    #pragma unroll
    for (int l = 0; l < 4; ++l) {
      const int v = t + l * 256;
      const int r = v >> 4, c4 = (v & 15) << 2;
      *(float4*)(Bsave + r * MIND + j0 + c4) =
          *(const float4*)(A + (size_t)(o + r) * MIND + j0 + c4);
    }
    return;
  }
  const int i0 = b * 64;
  if (i0 == o) return;
  const float* P = Pall + k * 4096;
  #pragma unroll
  for (int l = 0; l < 4; ++l) {
    const int v = t + l * 256;
    const int r = v >> 4, c4 = (v & 15) << 2;
    const float4 av = *(const float4*)(A + (size_t)(i0 + r) * MIND + o + c4);
    S1[(c4 + 0) * 68 + r] = av.x; S1[(c4 + 1) * 68 + r] = av.y;
    S1[(c4 + 2) * 68 + r] = av.z; S1[(c4 + 3) * 68 + r] = av.w;
    *(float4*)&S2[r * 68 + c4] = *(const float4*)(P + r * 64 + c4);
  }
  __syncthreads();
  const int ty = t >> 4, tx = t & 15;
  float acc[4][4] = {};
  for (int s = 0; s < 64; ++s) {
    const float4 a4 = *(const float4*)&S1[s * 68 + ty * 4];
    const float4 b4 = *(const float4*)&S2[s * 68 + tx * 4];
    const float a[4] = {a4.x, a4.y, a4.z, a4.w};
    const float bb[4] = {b4.x, b4.y, b4.z, b4.w};
    #pragma unroll
    for (int i = 0; i < 4; ++i)
      #pragma unroll
      for (int j = 0; j < 4; ++j) acc[i][j] += a[i] * bb[j];
  }
  #pragma unroll
  for (int i = 0; i < 4; ++i) {
    float4 o4; o4.x = acc[i][0]; o4.y = acc[i][1]; o4.z = acc[i][2]; o4.w = acc[i][3];
    *(float4*)(CP + (i0 + ty * 4 + i) * 64 + tx * 4) = o4;
  }
}

__device__ __forceinline__ void d_gj_apply(
    float* __restrict__ A, float* __restrict__ Pall,
    const float* __restrict__ CP, const float* __restrict__ Bsave, int k,
    int i0, int j0, float* S1, float* S2)
{
  const int o = k * 64;
  const int t = threadIdx.x;

  if (i0 == o && j0 == o) return;

  if (j0 == o) {                       // col: A_io = -CP_i (negated copy)
    #pragma unroll
    for (int l = 0; l < 4; ++l) {
      const int v = t + l * 256;
      const int r = v >> 4, c4 = (v & 15) << 2;
      float4 x = *(const float4*)(CP + (i0 + r) * 64 + c4);
      x.x = -x.x; x.y = -x.y; x.z = -x.z; x.w = -x.w;
      *(float4*)(A + (size_t)(i0 + r) * MIND + o + c4) = x;
    }
    return;
  }

  __syncthreads();                     // LDS may be in use by previous call
  #define DD(r, c) S1[(r) * 68 + (c)]
  const bool isrow = (i0 == o);
  const float* Lsrc = isrow ? (Pall + k * 4096) : (CP + i0 * 64);
  #pragma unroll
  for (int l = 0; l < 4; ++l) {
    const int v = t + l * 256;
    const int r = v >> 4, c4 = (v & 15) << 2;
    const float4 lv = *(const float4*)(Lsrc + r * 64 + c4);
    S1[(c4 + 0) * 68 + r] = lv.x; S1[(c4 + 1) * 68 + r] = lv.y;
    S1[(c4 + 2) * 68 + r] = lv.z; S1[(c4 + 3) * 68 + r] = lv.w;
    *(float4*)&S2[r * 68 + c4] = *(const float4*)(Bsave + r * MIND + j0 + c4);
  }
  __syncthreads();
  const int ty = t >> 4, tx = t & 15;
  float acc[4][4] = {};
  for (int s = 0; s < 64; ++s) {
    const float4 a4 = *(const float4*)&S1[s * 68 + ty * 4];
    const float4 b4 = *(const float4*)&S2[s * 68 + tx * 4];
    const float a[4] = {a4.x, a4.y, a4.z, a4.w};
    const float bb[4] = {b4.x, b4.y, b4.z, b4.w};
    #pragma unroll
    for (int i = 0; i < 4; ++i)
      #pragma unroll
      for (int j = 0; j < 4; ++j) acc[i][j] += a[i] * bb[j];
  }

  if (isrow) {                         // A_oj = P * Bsave_j
    #pragma unroll
    for (int i = 0; i < 4; ++i) {
      float4 o4; o4.x = acc[i][0]; o4.y = acc[i][1]; o4.z = acc[i][2]; o4.w = acc[i][3];
      *(float4*)(A + (size_t)(o + ty * 4 + i) * MIND + j0 + tx * 4) = o4;
    }
    return;
  }

  const bool isdiagnext = (i0 == o + 64) && (j0 == o + 64);
  if (!isdiagnext) {                   // big: A_ij -= CP_i * Bsave_j
    #pragma unroll
    for (int i = 0; i < 4; ++i) {
      float* cp = A + (size_t)(i0 + ty * 4 + i) * MIND + j0 + tx * 4;
      float4 cv = *(const float4*)cp;
      cv.x -= acc[i][0]; cv.y -= acc[i][1]; cv.z -= acc[i][2]; cv.w -= acc[i][3];
      *(float4*)cp = cv;
    }
    return;
  }

  // diag-next: update into LDS, run 64-step pivot loop, emit Pall[k+1] + A
  __syncthreads();                     // S1 readers done
  #pragma unroll
  for (int i = 0; i < 4; ++i) {
    const float4 cv = *(const float4*)(A + (size_t)(i0 + ty * 4 + i) * MIND + j0 + tx * 4);
    DD(ty * 4 + i, tx * 4 + 0) = cv.x - acc[i][0];
    DD(ty * 4 + i, tx * 4 + 1) = cv.y - acc[i][1];
    DD(ty * 4 + i, tx * 4 + 2) = cv.z - acc[i][2];
    DD(ty * 4 + i, tx * 4 + 3) = cv.w - acc[i][3];
  }
  __syncthreads();
  const int di = t >> 2, c0 = (t & 3) * 16;
  for (int s = 0; s < 64; ++s) {
    const float p = 1.0f / DD(s, s);
    if (t < 64 && t != s) DD(s, t) *= p;
    __syncthreads();
    if (di != s) {
      const float f = DD(di, s);
      #pragma unroll
      for (int c = c0; c < c0 + 16; c += 4) {
        float4 ds = *(const float4*)&DD(s, c);
        float4 dv = *(const float4*)&DD(di, c);
        dv.x -= f * ds.x; dv.y -= f * ds.y; dv.z -= f * ds.z; dv.w -= f * ds.w;
        *(float4*)&DD(di, c) = dv;
      }
      if (s >= c0 && s < c0 + 16) DD(di, s) = -f * p;
    }
    if (t == 0) DD(s, s) = p;
    __syncthreads();
  }
  float* Pn = Pall + (size_t)(k + 1) * 4096;
  #pragma unroll
  for (int l = 0; l < 4; ++l) {
    const int v = t + l * 256;
    const int r = v >> 4, c4 = (v & 15) << 2;
    const float4 dv = *(const float4*)&DD(r, c4);
    *(float4*)(Pn + r * 64 + c4) = dv;
    *(float4*)(A + (size_t)(i0 + r) * MIND + j0 + c4) = dv;
  }
  #undef DD
}

// R tile = Ai * ip  (64x64), K = MIND
__device__ __forceinline__ void d_gemm_f32(
    const float* __restrict__ A, const float* __restrict__ B,
    float* __restrict__ C, int bm, int bn, float* S1, float* S2)
{
  constexpr int BK = 16;
  const int tid = threadIdx.x;
  const int tx = tid % 16, ty = tid / 16;
  float acc[4][4] = {};
  const float* Ag = A + (size_t)bm * 64 * MIND;
  const float* Bg = B + bn * 64;
  for (int k0 = 0; k0 < MIND; k0 += BK) {
    {
      const int r = tid >> 2, c4 = (tid & 3) << 2;
      const float4 av = *(const float4*)(Ag + (size_t)r * MIND + k0 + c4);
      S1[(c4 + 0) * 68 + r] = av.x; S1[(c4 + 1) * 68 + r] = av.y;
      S1[(c4 + 2) * 68 + r] = av.z; S1[(c4 + 3) * 68 + r] = av.w;
      const int kr = tid / 16, nc = (tid % 16) << 2;
      *(float4*)&S2[kr * 68 + nc] = *(const float4*)(Bg + (size_t)(k0 + kr) * NF + nc);
    }
    __syncthreads();
    #pragma unroll
    for (int kk = 0; kk < BK; ++kk) {
      const float4 a4 = *(const float4*)&S1[kk * 68 + ty * 4];
      const float4 b4 = *(const float4*)&S2[kk * 68 + tx * 4];
      const float a[4] = {a4.x, a4.y, a4.z, a4.w};
      const float bb[4] = {b4.x, b4.y, b4.z, b4.w};
      #pragma unroll
      for (int i = 0; i < 4; ++i)
        #pragma unroll
        for (int j = 0; j < 4; ++j) acc[i][j] += a[i] * bb[j];
    }
    __syncthreads();
  }
  #pragma unroll
  for (int i = 0; i < 4; ++i) {
    float4 o4; o4.x = acc[i][0]; o4.y = acc[i][1]; o4.z = acc[i][2]; o4.w = acc[i][3];
    *(float4*)(C + (size_t)(bm * 64 + ty * 4 + i) * NF + bn * 64 + tx * 4) = o4;
  }
}

// u = rowsum(Ai) AND Kih = fp16(Ai), rows rg*4..rg*4+3 (no LDS)
__device__ __forceinline__ void d_rowsum_cast(
    const float* __restrict__ Ai, float* __restrict__ u,
    _Float16* __restrict__ Kih, int rg)
{
  const int row = rg * 4 + (threadIdx.x >> 6);
  const int lane = threadIdx.x & 63;
  const float* src = Ai + (size_t)row * MIND;
  _Float16* dst = Kih + (size_t)row * MIND;
  float s = 0.f;
  #pragma unroll
  for (int it = 0; it < 8; ++it) {
    const int c = it * 256 + lane * 4;
    const float4 v = *(const float4*)(src + c);
    s += v.x + v.y + v.z + v.w;
    half4v h; h.x = (_Float16)v.x; h.y = (_Float16)v.y;
    h.z = (_Float16)v.z; h.w = (_Float16)v.w;
    *(half4v*)(dst + c) = h;
  }
  #pragma unroll
  for (int off = 32; off; off >>= 1) s += __shfl_xor(s, off);
  if (lane == 0) u[row] = s;
}

// Rt tile + colsumR partials; T[64][65] in S1, psum[4][64] in S2
__device__ __forceinline__ void d_transpose_colsum(
    const float* __restrict__ R, _Float16* __restrict__ Rt,
    float* __restrict__ cs, int j0, int f0, float* S1, float* S2)
{
  const int t = threadIdx.x;
  #pragma unroll
  for (int l = 0; l < 16; ++l) {
    const int idx = t + l * 256;
    S1[(idx >> 6) * 65 + (idx & 63)] =
        R[(size_t)(j0 + (idx >> 6)) * NF + f0 + (idx & 63)];
  }
  __syncthreads();
  #pragma unroll
  for (int l = 0; l < 16; ++l) {
    const int idx = t + l * 256;
    const int fr = idx >> 6, jc = idx & 63;
    Rt[(size_t)(f0 + fr) * MIND + j0 + jc] = (_Float16)S1[jc * 65 + fr];
  }
  const int f = t & 63, q = t >> 6;
  float s = 0.f;
  #pragma unroll
  for (int j = q * 16; j < q * 16 + 16; ++j) s += S1[j * 65 + f];
  S2[q * 64 + f] = s;
  __syncthreads();
  if (t < 64)
    atomicAdd(&cs[f0 + t], S2[0 * 64 + t] + S2[1 * 64 + t] +
                           S2[2 * 64 + t] + S2[3 * 64 + t]);
}

__global__ __launch_bounds__(256, 2) void fused_gj(
    float* __restrict__ A, float* __restrict__ Pall,
    float* __restrict__ CP, float* __restrict__ Bsave,
    const float* __restrict__ ip, float* __restrict__ R,
    _Float16* __restrict__ Rt, float* __restrict__ colsumR,
    float* __restrict__ u, _Float16* __restrict__ Kih,
    int* __restrict__ bcnt, int* __restrict__ bgen)
{
  __shared__ float S1[64 * 68];
  __shared__ float S2[64 * 68];
  const int b = blockIdx.x;                 // 0..511

  if (b == 0) d_gj_diag(A, Pall, 0, S1);
  gbar(bcnt, bgen, GJ_BLOCKS);
  if (b < 64) d_gj_prep(A, Pall, CP, Bsave, 0, b, S1, S2);
  gbar(bcnt, bgen, GJ_BLOCKS);

  for (int k = 0; k < 32; ++k) {
    // 1024 apply tiles over 512 blocks: 2 sequential, independent tiles
    {
      const int t0 = b, t1 = b + 512;
      d_gj_apply(A, Pall, CP, Bsave, k, (t0 >> 5) * 64, (t0 & 31) * 64, S1, S2);
      d_gj_apply(A, Pall, CP, Bsave, k, (t1 >> 5) * 64, (t1 & 31) * 64, S1, S2);
    }
    gbar(bcnt, bgen, GJ_BLOCKS);
    if (k < 31) {
      if (b < 64) d_gj_prep(A, Pall, CP, Bsave, k + 1, b, S1, S2);
      gbar(bcnt, bgen, GJ_BLOCKS);
    }
  }

  // post: R = Kinv*ip (b<256) || u + Kih (b in [256,512), 2 row-groups each)
  if (b < 256) {
    d_gemm_f32(A, ip, R, b >> 3, b & 7, S1, S2);
  } else {
    d_rowsum_cast(A, u, Kih, (b - 256) * 2);
    d_rowsum_cast(A, u, Kih, (b - 256) * 2 + 1);
  }
  gbar(bcnt, bgen, GJ_BLOCKS);
  // Rt = fp16(R^T) + colsumR (b<256)
  if (b < 256)
    d_transpose_colsum(R, Rt, colsumR, (b & 31) * 64, (b >> 5) * 64, S1, S2);
}

// ----------------------------------------------------------- helpers -------
__global__ __launch_bounds__(256) void var_finalize(
    const float* __restrict__ varacc, const int* __restrict__ mask,
    float* __restrict__ outv)
{
  const int i = blockIdx.x * 256 + threadIdx.x;
  const float m = (mask[i] != 0) ? 1.f : 0.f;
  outv[i] = (1.0f - varacc[i]) * m;
}

}  // namespace

extern "C" void kernel_launch(void* const* d_in, const int* in_sizes, int n_in,
                              void* d_out, int out_size, void* d_ws, size_t ws_size,
                              hipStream_t stream)
{
  (void)in_sizes; (void)n_in; (void)out_size; (void)ws_size;
  const float* x     = (const float*)d_in[0];
  const int*   mask  = (const int*)d_in[1];
  const float* ip    = (const float*)d_in[2];
  const float* gamma = (const float*)d_in[3];
  float* out = (float*)d_out;

  float* w       = (float*)d_ws;
  float* sum     = w;                     // 512
  float* sumsq   = w + 512;               // 512
  float* cnt     = w + 1024;              // 1 (padded to 1536)
  int*   bcnt    = (int*)(w + 1040);      // grid-barrier count (zeroed)
  int*   bgen    = (int*)(w + 1041);      // grid-barrier generation (zeroed)
  float* varacc  = w + 1536;              // 16384
  float* colsumR = w + 17920;             // 512   -> [0, 18432) zeroed
  float* meanv   = w + 18432;
  float* stdv    = w + 18944;
  float* zsv     = w + 19456;
  float* giv     = w + 19968;
  float* rnorm   = w + 20480;             // 16384  } rnorm||cnorm contiguous
  float* cnorm   = w + 36864;             // 2048   }
  float* u       = w + 38912;             // 2048
  float* Ai      = w + 40960;             // 2048*2048 (Kreg -> Kinv in place)
  float* R       = w + 4235264;           // 2048*512
  float* Pall    = w + 5283840;           // 32*4096 pivot inverses
  float* CP      = w + 5414912;           // 2048*64
  float* Bsave   = w + 5545984;           // 64*2048
  _Float16* hb   = (_Float16*)(w + 5677056);
  _Float16* Zh   = hb;                    // 16384*512 } Zh||Zih contiguous
  _Float16* Zih  = hb + 8388608;          // 2048*512  }
  _Float16* DK   = hb + 9437184;          // 16384*2048
  _Float16* Kih  = hb + 42991616;         // 2048*2048 } Kih||Rt contiguous
  _Float16* Rt   = hb + 47185920;         // 512*2048  }

  hipMemsetAsync(w, 0, 18432 * sizeof(float), stream);

  stats_kernel<<<256, 256, 0, stream>>>(x, mask, sum, sumsq, cnt);
  finalize_stats<<<2, 256, 0, stream>>>(sum, sumsq, cnt, gamma, meanv, stdv, zsv, giv);
  make_z<<<NROW + MIND, 256, 0, stream>>>(x, mask, ip, meanv, zsv, giv, Zh, Zih, rnorm, cnorm);

  // PASS 0: A' = [Zh;Zih] -> DK (bm<64) + Kreg/Ai (bm>=64), XCD-swizzled
  mfma_gemm256f<0><<<dim3(MIND / 256, (NROW + MIND) / 256), 512, 0, stream>>>(
      Zh, Zih, NF, rnorm, cnorm,
      DK, Ai, nullptr, nullptr, nullptr, nullptr, nullptr, nullptr, nullptr);

  // Gauss-Jordan + {R, Rt, colsumR, u, Kih}: ONE plain launch, manual grid
  // barrier (512 blocks = 2/CU, co-resident with 2x resource margin)
  fused_gj<<<GJ_BLOCKS, 256, 0, stream>>>(
      Ai, Pall, CP, Bsave, ip, R, Rt, colsumR, u, Kih, bcnt, bgen);

  // PASS 1: B' = [Kih;Rt] -> varacc (bn<8) + x_new (bn>=8), XCD-swizzled;
  // DK A-panels staged once for both outputs
  mfma_gemm256f<1><<<dim3((MIND + NF) / 256, NROW / 256), 512, 0, stream>>>(
      DK, Kih, MIND, nullptr, nullptr,
      nullptr, out, DK, u, varacc, colsumR, stdv, meanv, mask);

  var_finalize<<<NROW / 256, 256, 0, stream>>>(varacc, mask, out + (size_t)NROW * NF);
}

// Round 8
// 2280.735 us; speedup vs baseline: 3.0064x; 3.0064x over previous
//
#include <hip/hip_runtime.h>
#include <math.h>
#include <stdint.h>

namespace {

constexpr int NROW = 16384;   // B*A
constexpr int NF   = 512;     // n_in
constexpr int MIND = 2048;    // inducing points
constexpr float CC = 0.98f;   // centering constant: Kx = exp(-d), d ~ 0.004

typedef _Float16 half8 __attribute__((ext_vector_type(8)));
typedef _Float16 half4v __attribute__((ext_vector_type(4)));
typedef float floatx4 __attribute__((ext_vector_type(4)));

__device__ __forceinline__ void gload16(const void* g, void* l) {
  __builtin_amdgcn_global_load_lds(
      (__attribute__((address_space(1))) void*)g,
      (__attribute__((address_space(3))) void*)l, 16, 0, 0);
}

#define MEMFENCE asm volatile("" ::: "memory")
#define GATE(N) asm volatile("s_waitcnt vmcnt(" #N ")" ::: "memory")

// ---- ping-pong 64-step Gauss-Jordan pivot (1 sync/step) -------------------
// In-place-inverse transform, all reads from OLD buffer:
//   p = 1/old[s][s]
//   row s:   new[s][c] = old[s][c]*p (c!=s), new[s][s] = p
//   row i!=s: new[i][c] = old[i][c] - (f*p)*old[s][c] (c!=s), new[i][s] = -f*p
//            where f = old[i][s]
// 64 steps (even) -> result back in B0.  Thread t owns row t>>2, cols
// (t&3)*16..+15.  Saves 64 __syncthreads vs the 2-sync in-place version.
__device__ __forceinline__ void pivot_loop(float* B0, float* B1) {
  const int t = threadIdx.x;
  const int i = t >> 2, c0 = (t & 3) * 16;
  float* src = B0;
  float* dst = B1;
  for (int s = 0; s < 64; ++s) {
    const float p = 1.0f / src[s * 68 + s];
    const float f = src[i * 68 + s];
    const float fp = f * p;
    #pragma unroll
    for (int c4 = 0; c4 < 16; c4 += 4) {
      const int c = c0 + c4;
      const float4 mine = *(const float4*)&src[i * 68 + c];
      const float4 prow = *(const float4*)&src[s * 68 + c];
      float4 outv;
      if (i == s) {
        outv.x = prow.x * p; outv.y = prow.y * p;
        outv.z = prow.z * p; outv.w = prow.w * p;
        if (s == c + 0) outv.x = p;
        if (s == c + 1) outv.y = p;
        if (s == c + 2) outv.z = p;
        if (s == c + 3) outv.w = p;
      } else {
        outv.x = mine.x - fp * prow.x; outv.y = mine.y - fp * prow.y;
        outv.z = mine.z - fp * prow.z; outv.w = mine.w - fp * prow.w;
        if (s == c + 0) outv.x = -fp;
        if (s == c + 1) outv.y = -fp;
        if (s == c + 2) outv.z = -fp;
        if (s == c + 3) outv.w = -fp;
      }
      *(float4*)&dst[i * 68 + c] = outv;
    }
    __syncthreads();
    float* tmp = src; src = dst; dst = tmp;
  }
}

// ---------------------------------------------------------------- stats ----
__global__ __launch_bounds__(256) void stats_kernel(
    const float* __restrict__ x, const int* __restrict__ mask,
    float* __restrict__ sum, float* __restrict__ sumsq, float* __restrict__ cnt)
{
  const int t = threadIdx.x;
  const int row0 = blockIdx.x * 64;
  float s0 = 0.f, s1 = 0.f, q0 = 0.f, q1 = 0.f, c = 0.f;
  for (int r = 0; r < 64; ++r) {
    const int row = row0 + r;
    const float m = (mask[row] != 0) ? 1.f : 0.f;
    const float v0 = x[(size_t)row * NF + t];
    const float v1 = x[(size_t)row * NF + t + 256];
    s0 += m * v0; q0 += m * v0 * v0;
    s1 += m * v1; q1 += m * v1 * v1;
    c += m;
  }
  atomicAdd(&sum[t], s0);        atomicAdd(&sum[t + 256], s1);
  atomicAdd(&sumsq[t], q0);      atomicAdd(&sumsq[t + 256], q1);
  if (t == 0) atomicAdd(cnt, c);
}

__global__ __launch_bounds__(256) void finalize_stats(
    const float* __restrict__ sum, const float* __restrict__ sumsq,
    const float* __restrict__ cnt, const float* __restrict__ gamma,
    float* __restrict__ meanv, float* __restrict__ stdv,
    float* __restrict__ zsv, float* __restrict__ giv)
{
  const int f = blockIdx.x * 256 + threadIdx.x;   // <<<2,256>>>
  const float n = cnt[0];
  const float mu = sum[f] / n;
  const float var = (sumsq[f] - sum[f] * mu) / (n - 1.0f);
  const float sd = sqrtf(var) + 1e-5f;
  const float g = gamma[f];
  const float g2 = g * g + 0.001f;
  meanv[f] = mu;
  stdv[f]  = sd;
  zsv[f]   = 1.0f / (sd * g2);
  giv[f]   = 1.0f / g2;
}

// z rows (masked, normalized, /g2) fp16 + zi rows fp16 + fp32 norms of the
// fp16-ROUNDED values (so d_jj ~ 0 exactly)
__global__ __launch_bounds__(256) void make_z(
    const float* __restrict__ x, const int* __restrict__ mask,
    const float* __restrict__ ip, const float* __restrict__ meanv,
    const float* __restrict__ zsv, const float* __restrict__ giv,
    _Float16* __restrict__ Zh, _Float16* __restrict__ Zih,
    float* __restrict__ rnorm, float* __restrict__ cnorm)
{
  const int row = blockIdx.x;
  const int t = threadIdx.x;
  float v0, v1;
  if (row < NROW) {
    const float m = (mask[row] != 0) ? 1.f : 0.f;
    v0 = (x[(size_t)row * NF + t      ] - meanv[t      ]) * zsv[t      ] * m;
    v1 = (x[(size_t)row * NF + t + 256] - meanv[t + 256]) * zsv[t + 256] * m;
    const _Float16 h0 = (_Float16)v0, h1 = (_Float16)v1;
    Zh[(size_t)row * NF + t] = h0;
    Zh[(size_t)row * NF + t + 256] = h1;
    v0 = (float)h0; v1 = (float)h1;
  } else {
    const int r = row - NROW;
    v0 = ip[(size_t)r * NF + t      ] * giv[t      ];
    v1 = ip[(size_t)r * NF + t + 256] * giv[t + 256];
    const _Float16 h0 = (_Float16)v0, h1 = (_Float16)v1;
    Zih[(size_t)r * NF + t] = h0;
    Zih[(size_t)r * NF + t + 256] = h1;
    v0 = (float)h0; v1 = (float)h1;
  }
  float nrm = v0 * v0 + v1 * v1;
  #pragma unroll
  for (int off = 32; off; off >>= 1) nrm += __shfl_xor(nrm, off);
  __shared__ float red[4];
  if ((t & 63) == 0) red[t >> 6] = nrm;
  __syncthreads();
  if (t == 0) {
    const float s = red[0] + red[1] + red[2] + red[3];
    if (row < NROW) rnorm[row] = s; else cnorm[row - NROW] = s;
  }
}

// ------------------------------------------------- 256x256 deep-pipe GEMM --
// (R5 proven version, unchanged: fused-by-concatenation, XCD swizzle,
//  LDS slot-swizzle, counted vmcnt(8) 4-buffer pipeline.)
template <int PASS>
__global__ __launch_bounds__(512, 2) void mfma_gemm256f(
    const _Float16* __restrict__ A, const _Float16* __restrict__ B, int K,
    const float* __restrict__ rn, const float* __restrict__ cn,
    _Float16* __restrict__ DKout, float* __restrict__ Cf,
    const _Float16* __restrict__ DK, const float* __restrict__ u,
    float* __restrict__ varacc,
    const float* __restrict__ colsumR, const float* __restrict__ stdv,
    const float* __restrict__ meanv, const int* __restrict__ mask)
{
  __shared__ __align__(16) _Float16 Asmem[4][256 * 32];
  __shared__ __align__(16) _Float16 Bsmem[4][256 * 32];

  const int tid = threadIdx.x;
  const int w = tid >> 6, L = tid & 63;
  const int wm = w >> 2, wn = w & 3;          // 2 x 4 waves
  const int lq = L >> 4, lr = L & 15;
  // ---- XCD-aware remap (T1): same-bm blocks contiguous on one XCD ----
  int bn, bm;
  if constexpr (PASS == 0) {
    const int wgid = blockIdx.y * 8 + blockIdx.x;    // grid (8,72)
    const int xcd = wgid & 7, q = wgid >> 3;         // q: 0..71
    bm = xcd + 8 * (q >> 3);                         // 0..71, bijective
    bn = q & 7;                                      // 0..7
  } else {
    const int wgid = blockIdx.y * 10 + blockIdx.x;   // grid (10,64)
    const int xcd = wgid & 7, q = wgid >> 3;         // q: 0..79
    bm = xcd + 8 * (q / 10);                         // 0..63, bijective
    bn = q % 10;                                     // 0..9
  }
  const int NT = K >> 5;                      // K tiles of 32

  // ---- staging maps (linear LDS dest = base + lane*16; swizzled global src)
  const int srow  = tid >> 2;                 // 0..127 (chunk j adds 128)
  const int sslot = tid & 3;                  // LDS 16B slot within 64B row
  const int gslot = sslot ^ ((tid >> 3) & 3); // swizzled source slot
  const _Float16* Ag = A + (size_t)(bm * 256 + srow) * K + gslot * 8;
  const _Float16* Bg = B + (size_t)(bn * 256 + srow) * K + gslot * 8;
  const size_t rstride = (size_t)128 * K;
  const int ldst = srow * 32 + sslot * 8;     // halves

  // ---- fragment read offsets (swizzled): slot = lq ^ ((lr>>1)&3)
  const int fswz = (lq ^ ((lr >> 1) & 3)) * 8;
  const int aoff = (wm * 128 + lr) * 32 + fswz;
  const int boff = (wn * 64  + lr) * 32 + fswz;

  floatx4 acc[8][4] = {};

  auto stageA = [&](int t) {
    _Float16* dst = Asmem[t & 3] + ldst;
    const _Float16* src = Ag + (size_t)t * 32;
    gload16(src, dst);
    gload16(src + rstride, dst + 128 * 32);
  };
  auto stageB = [&](int t) {
    _Float16* dst = Bsmem[t & 3] + ldst;
    const _Float16* src = Bg + (size_t)t * 32;
    gload16(src, dst);
    gload16(src + rstride, dst + 128 * 32);
  };

  // ---- prologue: stage tiles 0,1,2 (12 loads); gate tile 0 with vmcnt(8)
  stageA(0); stageB(0);
  if (NT > 1) { stageA(1); stageB(1); }
  if (NT > 2) { stageA(2); stageB(2); }
  if (NT > 2)      { GATE(8); }
  else if (NT > 1) { GATE(4); }
  else             { GATE(0); }
  __builtin_amdgcn_s_barrier();
  MEMFENCE;

  for (int t = 0; t < NT; ++t) {
    const _Float16* As = Asmem[t & 3];
    const _Float16* Bs = Bsmem[t & 3];
    half8 af[4], bf[4], af2[4];

    // ---- phase 0: quadrant mi0-3 --------------------------------------
    #pragma unroll
    for (int mi = 0; mi < 4; ++mi) af[mi] = *(const half8*)&As[aoff + mi * 512];
    #pragma unroll
    for (int ni = 0; ni < 4; ++ni) bf[ni] = *(const half8*)&Bs[boff + ni * 512];
    if (t + 3 < NT) stageA(t + 3);
    MEMFENCE;
    __builtin_amdgcn_s_barrier();
    MEMFENCE;
    __builtin_amdgcn_s_setprio(1);
    #pragma unroll
    for (int mi = 0; mi < 4; ++mi)
      #pragma unroll
      for (int ni = 0; ni < 4; ++ni)
        acc[mi][ni] = __builtin_amdgcn_mfma_f32_16x16x32_f16(
            af[mi], bf[ni], acc[mi][ni], 0, 0, 0);
    __builtin_amdgcn_s_setprio(0);

    // ---- phase 1: quadrant mi4-7 + counted-vmcnt gate for tile t+1 ----
    #pragma unroll
    for (int mi = 0; mi < 4; ++mi)
      af2[mi] = *(const half8*)&As[aoff + (mi + 4) * 512];
    if (t + 3 < NT) stageB(t + 3);
    // outstanding after this phase's stages: tiles {t+2 .. min(t+3,NT-1)}
    if (t + 4 <= NT)      { GATE(8); }   // 2 future tiles in flight
    else if (t + 3 == NT) { GATE(4); }   // 1 future tile
    else if (t + 2 == NT) { GATE(0); }   // drain before last tile
    __builtin_amdgcn_s_barrier();
    MEMFENCE;
    __builtin_amdgcn_s_setprio(1);
    #pragma unroll
    for (int mi = 0; mi < 4; ++mi)
      #pragma unroll
      for (int ni = 0; ni < 4; ++ni)
        acc[mi + 4][ni] = __builtin_amdgcn_mfma_f32_16x16x32_f16(
            af2[mi], bf[ni], acc[mi + 4][ni], 0, 0, 0);
    __builtin_amdgcn_s_setprio(0);
  }

  // ---- epilogue.  C/D layout: col = lane&15, row = (lane>>4)*4 + reg
  const int grb = bm * 256 + wm * 128;
  const int gcb = bn * 256 + wn * 64;

  if constexpr (PASS == 0) {
    if (bm < NROW / 256) {             // EPI0: Kx -> DK fp16
      #pragma unroll
      for (int mi = 0; mi < 8; ++mi)
        #pragma unroll
        for (int e = 0; e < 4; ++e) {
          const int gr = grb + mi * 16 + lq * 4 + e;
          const float rni = rn[gr];
          #pragma unroll
          for (int ni = 0; ni < 4; ++ni) {
            const int gc = gcb + ni * 16 + lr;
            const float d = rni + cn[gc] - 2.f * acc[mi][ni][e];
            DKout[(size_t)gr * MIND + gc] = (_Float16)(expf(-fabsf(d)) - CC);
          }
        }
    } else {                           // EPI1: Kreg fp32 (+0.05 I)
      #pragma unroll
      for (int mi = 0; mi < 8; ++mi)
        #pragma unroll
        for (int e = 0; e < 4; ++e) {
          const int gr = grb + mi * 16 + lq * 4 + e;
          const int gr2 = gr - NROW;
          const float rni = rn[gr];    // rn = rnorm||cnorm contiguous
          #pragma unroll
          for (int ni = 0; ni < 4; ++ni) {
            const int gc = gcb + ni * 16 + lr;
            const float d = rni + cn[gc] - 2.f * acc[mi][ni][e];
            float kx = expf(-fabsf(d));
            if (gr2 == gc) kx += 0.05f;
            Cf[(size_t)gr2 * MIND + gc] = kx;
          }
        }
    }
  } else {
    if (bn < MIND / 256) {             // EPI2: var reduction
      #pragma unroll
      for (int mi = 0; mi < 8; ++mi)
        #pragma unroll
        for (int e = 0; e < 4; ++e) {
          const int gr = grb + mi * 16 + lq * 4 + e;
          float partial = 0.f;
          #pragma unroll
          for (int ni = 0; ni < 4; ++ni) {
            const int gc = gcb + ni * 16 + lr;
            const float tv = acc[mi][ni][e] + CC * u[gc];
            partial += tv * (CC + (float)DK[(size_t)gr * MIND + gc]);
          }
          partial += __shfl_xor(partial, 1);
          partial += __shfl_xor(partial, 2);
          partial += __shfl_xor(partial, 4);
          partial += __shfl_xor(partial, 8);
          if (lr == 0) atomicAdd(&varacc[gr], partial);
        }
    } else {                           // EPI3: x_new
      const int gcb3 = (bn - MIND / 256) * 256 + wn * 64;
      #pragma unroll
      for (int mi = 0; mi < 8; ++mi)
        #pragma unroll
        for (int e = 0; e < 4; ++e) {
          const int gr = grb + mi * 16 + lq * 4 + e;
          const float mrow = (mask[gr] != 0) ? 1.f : 0.f;
          #pragma unroll
          for (int ni = 0; ni < 4; ++ni) {
            const int gc3 = gcb3 + ni * 16 + lr;
            const float v = acc[mi][ni][e] + CC * colsumR[gc3];
            Cf[(size_t)gr * NF + gc3] = (v * stdv[gc3] + meanv[gc3]) * mrow;
          }
        }
    }
  }
}

// ------------------------------------------------------------ fp32 GEMM ----
// C[M,N] = A[M,K]*B[K,N], 64x64 tile (R = Kinv * P only)
__global__ __launch_bounds__(256) void gemm_f32(
    const float* __restrict__ A, const float* __restrict__ B,
    float* __restrict__ C, int M, int N, int K)
{
  constexpr int BM = 64, BN = 64, BK = 16;
  const int tid = threadIdx.x;
  const int tx = tid % 16, ty = tid / 16;
  const int bn = blockIdx.x, bm = blockIdx.y;
  __shared__ float As[BK][BM + 4];
  __shared__ float Bs[BK][BN + 4];
  float acc[4][4] = {};
  const float* Ag = A + (size_t)bm * BM * K;
  const float* Bg = B + bn * BN;
  for (int k0 = 0; k0 < K; k0 += BK) {
    {
      const int r = tid >> 2, c4 = (tid & 3) << 2;
      const float4 av = *(const float4*)(Ag + (size_t)r * K + k0 + c4);
      As[c4 + 0][r] = av.x; As[c4 + 1][r] = av.y;
      As[c4 + 2][r] = av.z; As[c4 + 3][r] = av.w;
      const int kr = tid / 16, nc = (tid % 16) << 2;
      *(float4*)&Bs[kr][nc] = *(const float4*)(Bg + (size_t)(k0 + kr) * N + nc);
    }
    __syncthreads();
    #pragma unroll
    for (int kk = 0; kk < BK; ++kk) {
      const float4 a4 = *(const float4*)&As[kk][ty * 4];
      const float4 b4 = *(const float4*)&Bs[kk][tx * 4];
      const float a[4] = {a4.x, a4.y, a4.z, a4.w};
      const float b[4] = {b4.x, b4.y, b4.z, b4.w};
      #pragma unroll
      for (int i = 0; i < 4; ++i)
        #pragma unroll
        for (int j = 0; j < 4; ++j) acc[i][j] += a[i] * b[j];
    }
    __syncthreads();
  }
  #pragma unroll
  for (int i = 0; i < 4; ++i) {
    float4 o4; o4.x = acc[i][0]; o4.y = acc[i][1]; o4.z = acc[i][2]; o4.w = acc[i][3];
    *(float4*)(C + (size_t)(bm * BM + ty * 4 + i) * N + bn * BN + tx * 4) = o4;
  }
}

// ------------------------------------------------- blocked Gauss-Jordan ----
// Round-1 proven dataflow: 2 launches/iter.  Per iter k (o = 64k):
//   gj_apply: row A_oj = P*Bsave_j; col A_io = -CP_i; big A_ij -= CP_i*Bsave_j;
//             block (o+64,o+64) also runs the pivot loop -> Pall[k+1]
//   gj_prep:  CP_i = A[i][o']*P';  Bsave = copy of row panel A[o'][:]
// R8 changes: (a) ping-pong 1-sync pivot loop (was 2 syncs/step);
// (b) A-tile prefetched into regs before the LDS GEMM (hides RMW latency).

__global__ __launch_bounds__(256) void gj_diag(
    float* __restrict__ A, float* __restrict__ Pall, int k)
{
  const int o = k * 64;
  __shared__ float D0[64 * 68];
  __shared__ float D1[64 * 68];
  const int t = threadIdx.x;
  #pragma unroll
  for (int l = 0; l < 4; ++l) {
    const int v = t + l * 256;
    const int r = v >> 4, c4 = (v & 15) << 2;
    *(float4*)&D0[r * 68 + c4] = *(const float4*)(A + (size_t)(o + r) * MIND + o + c4);
  }
  __syncthreads();
  pivot_loop(D0, D1);                  // result in D0 (64 even steps)
  float* P = Pall + k * 4096;
  #pragma unroll
  for (int l = 0; l < 4; ++l) {
    const int v = t + l * 256;
    const int r = v >> 4, c4 = (v & 15) << 2;
    const float4 dv = *(const float4*)&D0[r * 68 + c4];
    *(float4*)(P + r * 64 + c4) = dv;
    *(float4*)(A + (size_t)(o + r) * MIND + o + c4) = dv;
  }
}

// 64 blocks: bx<32 -> CP_i = A[i][o]*P (skip i==o); bx>=32 -> Bsave row copy
__global__ __launch_bounds__(256) void gj_prep(
    const float* __restrict__ A, const float* __restrict__ Pall,
    float* __restrict__ CP, float* __restrict__ Bsave, int k)
{
  const int o = k * 64;
  const int t = threadIdx.x;
  if (blockIdx.x >= 32) {
    const int j0 = (blockIdx.x - 32) * 64;
    #pragma unroll
    for (int l = 0; l < 4; ++l) {
      const int v = t + l * 256;
      const int r = v >> 4, c4 = (v & 15) << 2;
      *(float4*)(Bsave + r * MIND + j0 + c4) =
          *(const float4*)(A + (size_t)(o + r) * MIND + j0 + c4);
    }
    return;
  }
  const int i0 = blockIdx.x * 64;
  if (i0 == o) return;
  const float* P = Pall + k * 4096;
  __shared__ float At[64][68];   // At[s][r] = A[i0+r][o+s]
  __shared__ float Pl[64][68];   // Pl[s][c] = P[s][c]
  #pragma unroll
  for (int l = 0; l < 4; ++l) {
    const int v = t + l * 256;
    const int r = v >> 4, c4 = (v & 15) << 2;
    const float4 av = *(const float4*)(A + (size_t)(i0 + r) * MIND + o + c4);
    At[c4 + 0][r] = av.x; At[c4 + 1][r] = av.y;
    At[c4 + 2][r] = av.z; At[c4 + 3][r] = av.w;
    *(float4*)&Pl[r][c4] = *(const float4*)(P + r * 64 + c4);
  }
  __syncthreads();
  const int ty = t >> 4, tx = t & 15;
  float acc[4][4] = {};
  for (int s = 0; s < 64; ++s) {
    const float4 a4 = *(const float4*)&At[s][ty * 4];
    const float4 b4 = *(const float4*)&Pl[s][tx * 4];
    const float a[4] = {a4.x, a4.y, a4.z, a4.w};
    const float b[4] = {b4.x, b4.y, b4.z, b4.w};
    #pragma unroll
    for (int i = 0; i < 4; ++i)
      #pragma unroll
      for (int j = 0; j < 4; ++j) acc[i][j] += a[i] * b[j];
  }
  #pragma unroll
  for (int i = 0; i < 4; ++i) {
    float4 o4; o4.x = acc[i][0]; o4.y = acc[i][1]; o4.z = acc[i][2]; o4.w = acc[i][3];
    *(float4*)(CP + (i0 + ty * 4 + i) * 64 + tx * 4) = o4;
  }
}

__global__ __launch_bounds__(256) void gj_apply(
    float* __restrict__ A, float* __restrict__ Pall,
    const float* __restrict__ CP, const float* __restrict__ Bsave, int k)
{
  const int o = k * 64;
  const int i0 = blockIdx.y * 64, j0 = blockIdx.x * 64;
  const int t = threadIdx.x;
  const int ty = t >> 4, tx = t & 15;

  if (i0 == o && j0 == o) return;

  if (j0 == o) {                       // col: A_io = -CP_i (negated copy)
    #pragma unroll
    for (int l = 0; l < 4; ++l) {
      const int v = t + l * 256;
      const int r = v >> 4, c4 = (v & 15) << 2;
      float4 x = *(const float4*)(CP + (i0 + r) * 64 + c4);
      x.x = -x.x; x.y = -x.y; x.z = -x.z; x.w = -x.w;
      *(float4*)(A + (size_t)(i0 + r) * MIND + o + c4) = x;
    }
    return;
  }

  __shared__ float S1[64 * 68];   // Lt (transposed left op); later pivot buf
  __shared__ float S2[64 * 68];   // Bsave tile; later pivot ping-pong buf
  #define DD(r, c) S1[(r) * 68 + (c)]

  const bool isrow = (i0 == o);

  // ---- prefetch this block's A tile (hides RMW latency under the GEMM) --
  float4 cv[4];
  if (!isrow) {
    const float* ap = A + (size_t)(i0 + ty * 4) * MIND + j0 + tx * 4;
    #pragma unroll
    for (int i = 0; i < 4; ++i) cv[i] = *(const float4*)(ap + (size_t)i * MIND);
  }

  const float* Lsrc = isrow ? (Pall + k * 4096) : (CP + i0 * 64);
  #pragma unroll
  for (int l = 0; l < 4; ++l) {
    const int v = t + l * 256;
    const int r = v >> 4, c4 = (v & 15) << 2;
    const float4 lv = *(const float4*)(Lsrc + r * 64 + c4);
    S1[(c4 + 0) * 68 + r] = lv.x; S1[(c4 + 1) * 68 + r] = lv.y;
    S1[(c4 + 2) * 68 + r] = lv.z; S1[(c4 + 3) * 68 + r] = lv.w;
    *(float4*)&S2[r * 68 + c4] = *(const float4*)(Bsave + r * MIND + j0 + c4);
  }
  __syncthreads();
  float acc[4][4] = {};
  for (int s = 0; s < 64; ++s) {
    const float4 a4 = *(const float4*)&S1[s * 68 + ty * 4];
    const float4 b4 = *(const float4*)&S2[s * 68 + tx * 4];
    const float a[4] = {a4.x, a4.y, a4.z, a4.w};
    const float b[4] = {b4.x, b4.y, b4.z, b4.w};
    #pragma unroll
    for (int i = 0; i < 4; ++i)
      #pragma unroll
      for (int j = 0; j < 4; ++j) acc[i][j] += a[i] * b[j];
  }

  if (isrow) {                         // A_oj = P * Bsave_j
    #pragma unroll
    for (int i = 0; i < 4; ++i) {
      float4 o4; o4.x = acc[i][0]; o4.y = acc[i][1]; o4.z = acc[i][2]; o4.w = acc[i][3];
      *(float4*)(A + (size_t)(o + ty * 4 + i) * MIND + j0 + tx * 4) = o4;
    }
    return;
  }

  const bool isdiagnext = (i0 == o + 64) && (j0 == o + 64);
  if (!isdiagnext) {                   // big: A_ij -= CP_i * Bsave_j
    #pragma unroll
    for (int i = 0; i < 4; ++i) {
      float4 nv = cv[i];
      nv.x -= acc[i][0]; nv.y -= acc[i][1]; nv.z -= acc[i][2]; nv.w -= acc[i][3];
      *(float4*)(A + (size_t)(i0 + ty * 4 + i) * MIND + j0 + tx * 4) = nv;
    }
    return;
  }

  // diag-next: update into LDS, ping-pong pivot loop, emit Pall[k+1] + A
  __syncthreads();                     // S1/S2 readers done
  #pragma unroll
  for (int i = 0; i < 4; ++i) {
    DD(ty * 4 + i, tx * 4 + 0) = cv[i].x - acc[i][0];
    DD(ty * 4 + i, tx * 4 + 1) = cv[i].y - acc[i][1];
    DD(ty * 4 + i, tx * 4 + 2) = cv[i].z - acc[i][2];
    DD(ty * 4 + i, tx * 4 + 3) = cv[i].w - acc[i][3];
  }
  __syncthreads();
  pivot_loop(S1, S2);                  // result in S1 (64 even steps)
  float* Pn = Pall + (size_t)(k + 1) * 4096;
  #pragma unroll
  for (int l = 0; l < 4; ++l) {
    const int v = t + l * 256;
    const int r = v >> 4, c4 = (v & 15) << 2;
    const float4 dv = *(const float4*)&DD(r, c4);
    *(float4*)(Pn + r * 64 + c4) = dv;
    *(float4*)(A + (size_t)(i0 + r) * MIND + j0 + c4) = dv;
  }
  #undef DD
}

// ----------------------------------------------------------- helpers -------
// u = rowsum(Ai) AND Kih = fp16(Ai) in one pass (one 16.8 MB read, not two)
__global__ __launch_bounds__(256) void rowsum_cast(
    const float* __restrict__ Ai, float* __restrict__ u,
    _Float16* __restrict__ Kih)
{
  const int row = blockIdx.x * 4 + (threadIdx.x >> 6);
  const int lane = threadIdx.x & 63;
  const float* src = Ai + (size_t)row * MIND;
  _Float16* dst = Kih + (size_t)row * MIND;
  float s = 0.f;
  #pragma unroll
  for (int it = 0; it < 8; ++it) {
    const int c = it * 256 + lane * 4;
    const float4 v = *(const float4*)(src + c);
    s += v.x + v.y + v.z + v.w;
    half4v h; h.x = (_Float16)v.x; h.y = (_Float16)v.y;
    h.z = (_Float16)v.z; h.w = (_Float16)v.w;
    *(half4v*)(dst + c) = h;
  }
  #pragma unroll
  for (int off = 32; off; off >>= 1) s += __shfl_xor(s, off);
  if (lane == 0) u[row] = s;
}

// Rt[512,2048] = fp16(R[2048,512]^T) AND colsumR partial sums (one R read)
__global__ __launch_bounds__(256) void transpose_colsum(
    const float* __restrict__ R, _Float16* __restrict__ Rt,
    float* __restrict__ cs)
{
  __shared__ float T[64][65];
  __shared__ float psum[4][64];
  const int j0 = blockIdx.x * 64;
  const int f0 = blockIdx.y * 64;
  const int t = threadIdx.x;
  #pragma unroll
  for (int l = 0; l < 16; ++l) {
    const int idx = t + l * 256;
    T[idx >> 6][idx & 63] = R[(size_t)(j0 + (idx >> 6)) * NF + f0 + (idx & 63)];
  }
  __syncthreads();
  #pragma unroll
  for (int l = 0; l < 16; ++l) {
    const int idx = t + l * 256;
    const int fr = idx >> 6, jc = idx & 63;
    Rt[(size_t)(f0 + fr) * MIND + j0 + jc] = (_Float16)T[jc][fr];
  }
  const int f = t & 63, q = t >> 6;
  float s = 0.f;
  #pragma unroll
  for (int j = q * 16; j < q * 16 + 16; ++j) s += T[j][f];
  psum[q][f] = s;
  __syncthreads();
  if (t < 64) atomicAdd(&cs[f0 + t], psum[0][t] + psum[1][t] + psum[2][t] + psum[3][t]);
}

__global__ __launch_bounds__(256) void var_finalize(
    const float* __restrict__ varacc, const int* __restrict__ mask,
    float* __restrict__ outv)
{
  const int i = blockIdx.x * 256 + threadIdx.x;
  const float m = (mask[i] != 0) ? 1.f : 0.f;
  outv[i] = (1.0f - varacc[i]) * m;
}

}  // namespace

extern "C" void kernel_launch(void* const* d_in, const int* in_sizes, int n_in,
                              void* d_out, int out_size, void* d_ws, size_t ws_size,
                              hipStream_t stream)
{
  (void)in_sizes; (void)n_in; (void)out_size; (void)ws_size;
  const float* x     = (const float*)d_in[0];
  const int*   mask  = (const int*)d_in[1];
  const float* ip    = (const float*)d_in[2];
  const float* gamma = (const float*)d_in[3];
  float* out = (float*)d_out;

  float* w       = (float*)d_ws;
  float* sum     = w;                     // 512
  float* sumsq   = w + 512;               // 512
  float* cnt     = w + 1024;              // 1 (padded 512)
  float* varacc  = w + 1536;              // 16384
  float* colsumR = w + 17920;             // 512   -> [0, 18432) zeroed
  float* meanv   = w + 18432;
  float* stdv    = w + 18944;
  float* zsv     = w + 19456;
  float* giv     = w + 19968;
  float* rnorm   = w + 20480;             // 16384  } rnorm||cnorm contiguous
  float* cnorm   = w + 36864;             // 2048   }
  float* u       = w + 38912;             // 2048
  float* Ai      = w + 40960;             // 2048*2048 (Kreg -> Kinv in place)
  float* R       = w + 4235264;           // 2048*512
  float* Pall    = w + 5283840;           // 32*4096 pivot inverses
  float* CP      = w + 5414912;           // 2048*64
  float* Bsave   = w + 5545984;           // 64*2048
  _Float16* hb   = (_Float16*)(w + 5677056);
  _Float16* Zh   = hb;                    // 16384*512 } Zh||Zih contiguous
  _Float16* Zih  = hb + 8388608;          // 2048*512  }
  _Float16* DK   = hb + 9437184;          // 16384*2048
  _Float16* Kih  = hb + 42991616;         // 2048*2048 } Kih||Rt contiguous
  _Float16* Rt   = hb + 47185920;         // 512*2048  }

  hipMemsetAsync(w, 0, 18432 * sizeof(float), stream);

  stats_kernel<<<256, 256, 0, stream>>>(x, mask, sum, sumsq, cnt);
  finalize_stats<<<2, 256, 0, stream>>>(sum, sumsq, cnt, gamma, meanv, stdv, zsv, giv);
  make_z<<<NROW + MIND, 256, 0, stream>>>(x, mask, ip, meanv, zsv, giv, Zh, Zih, rnorm, cnorm);

  // PASS 0: A' = [Zh;Zih] -> DK (bm<64) + Kreg/Ai (bm>=64), XCD-swizzled
  mfma_gemm256f<0><<<dim3(MIND / 256, (NROW + MIND) / 256), 512, 0, stream>>>(
      Zh, Zih, NF, rnorm, cnorm,
      DK, Ai, nullptr, nullptr, nullptr, nullptr, nullptr, nullptr, nullptr);

  // blocked Gauss-Jordan inverse, 2 launches/iter, diag hidden in apply
  gj_diag<<<1, 256, 0, stream>>>(Ai, Pall, 0);
  gj_prep<<<64, 256, 0, stream>>>(Ai, Pall, CP, Bsave, 0);
  for (int k = 0; k < 32; ++k) {
    gj_apply<<<dim3(32, 32), 256, 0, stream>>>(Ai, Pall, CP, Bsave, k);
    if (k < 31) gj_prep<<<64, 256, 0, stream>>>(Ai, Pall, CP, Bsave, k + 1);
  }

  // R = Kinv * P (fp32); Rt + colsumR fused; u + Kih fused
  gemm_f32<<<dim3(NF / 64, MIND / 64), 256, 0, stream>>>(Ai, ip, R, MIND, NF, MIND);
  transpose_colsum<<<dim3(MIND / 64, NF / 64), 256, 0, stream>>>(R, Rt, colsumR);
  rowsum_cast<<<MIND / 4, 256, 0, stream>>>(Ai, u, Kih);

  // PASS 1: B' = [Kih;Rt] -> varacc (bn<8) + x_new (bn>=8), XCD-swizzled;
  // DK A-panels staged once for both outputs
  mfma_gemm256f<1><<<dim3((MIND + NF) / 256, NROW / 256), 512, 0, stream>>>(
      DK, Kih, MIND, nullptr, nullptr,
      nullptr, out, DK, u, varacc, colsumR, stdv, meanv, mask);

  var_finalize<<<NROW / 256, 256, 0, stream>>>(varacc, mask, out + (size_t)NROW * NF);
}

// Round 9
// 2031.921 us; speedup vs baseline: 3.3746x; 1.1225x over previous
//
#include <hip/hip_runtime.h>
#include <math.h>
#include <stdint.h>

namespace {

constexpr int NROW = 16384;   // B*A
constexpr int NF   = 512;     // n_in
constexpr int MIND = 2048;    // inducing points
constexpr float CC = 0.98f;   // centering constant: Kx = exp(-d), d ~ 0.004

typedef _Float16 half8 __attribute__((ext_vector_type(8)));
typedef _Float16 half4v __attribute__((ext_vector_type(4)));
typedef float floatx4 __attribute__((ext_vector_type(4)));

__device__ __forceinline__ void gload16(const void* g, void* l) {
  __builtin_amdgcn_global_load_lds(
      (__attribute__((address_space(1))) void*)g,
      (__attribute__((address_space(3))) void*)l, 16, 0, 0);
}

#define MEMFENCE asm volatile("" ::: "memory")
#define GATE(N) asm volatile("s_waitcnt vmcnt(" #N ")" ::: "memory")

// ---------------------------------------------------------------- stats ----
__global__ __launch_bounds__(256) void stats_kernel(
    const float* __restrict__ x, const int* __restrict__ mask,
    float* __restrict__ sum, float* __restrict__ sumsq, float* __restrict__ cnt)
{
  const int t = threadIdx.x;
  const int row0 = blockIdx.x * 64;
  float s0 = 0.f, s1 = 0.f, q0 = 0.f, q1 = 0.f, c = 0.f;
  for (int r = 0; r < 64; ++r) {
    const int row = row0 + r;
    const float m = (mask[row] != 0) ? 1.f : 0.f;
    const float v0 = x[(size_t)row * NF + t];
    const float v1 = x[(size_t)row * NF + t + 256];
    s0 += m * v0; q0 += m * v0 * v0;
    s1 += m * v1; q1 += m * v1 * v1;
    c += m;
  }
  atomicAdd(&sum[t], s0);        atomicAdd(&sum[t + 256], s1);
  atomicAdd(&sumsq[t], q0);      atomicAdd(&sumsq[t + 256], q1);
  if (t == 0) atomicAdd(cnt, c);
}

__global__ __launch_bounds__(256) void finalize_stats(
    const float* __restrict__ sum, const float* __restrict__ sumsq,
    const float* __restrict__ cnt, const float* __restrict__ gamma,
    float* __restrict__ meanv, float* __restrict__ stdv,
    float* __restrict__ zsv, float* __restrict__ giv)
{
  const int f = blockIdx.x * 256 + threadIdx.x;   // <<<2,256>>>
  const float n = cnt[0];
  const float mu = sum[f] / n;
  const float var = (sumsq[f] - sum[f] * mu) / (n - 1.0f);
  const float sd = sqrtf(var) + 1e-5f;
  const float g = gamma[f];
  const float g2 = g * g + 0.001f;
  meanv[f] = mu;
  stdv[f]  = sd;
  zsv[f]   = 1.0f / (sd * g2);
  giv[f]   = 1.0f / g2;
}

// z rows (masked, normalized, /g2) fp16 + zi rows fp16 + fp32 norms of the
// fp16-ROUNDED values (so d_jj ~ 0 exactly)
__global__ __launch_bounds__(256) void make_z(
    const float* __restrict__ x, const int* __restrict__ mask,
    const float* __restrict__ ip, const float* __restrict__ meanv,
    const float* __restrict__ zsv, const float* __restrict__ giv,
    _Float16* __restrict__ Zh, _Float16* __restrict__ Zih,
    float* __restrict__ rnorm, float* __restrict__ cnorm)
{
  const int row = blockIdx.x;
  const int t = threadIdx.x;
  float v0, v1;
  if (row < NROW) {
    const float m = (mask[row] != 0) ? 1.f : 0.f;
    v0 = (x[(size_t)row * NF + t      ] - meanv[t      ]) * zsv[t      ] * m;
    v1 = (x[(size_t)row * NF + t + 256] - meanv[t + 256]) * zsv[t + 256] * m;
    const _Float16 h0 = (_Float16)v0, h1 = (_Float16)v1;
    Zh[(size_t)row * NF + t] = h0;
    Zh[(size_t)row * NF + t + 256] = h1;
    v0 = (float)h0; v1 = (float)h1;
  } else {
    const int r = row - NROW;
    v0 = ip[(size_t)r * NF + t      ] * giv[t      ];
    v1 = ip[(size_t)r * NF + t + 256] * giv[t + 256];
    const _Float16 h0 = (_Float16)v0, h1 = (_Float16)v1;
    Zih[(size_t)r * NF + t] = h0;
    Zih[(size_t)r * NF + t + 256] = h1;
    v0 = (float)h0; v1 = (float)h1;
  }
  float nrm = v0 * v0 + v1 * v1;
  #pragma unroll
  for (int off = 32; off; off >>= 1) nrm += __shfl_xor(nrm, off);
  __shared__ float red[4];
  if ((t & 63) == 0) red[t >> 6] = nrm;
  __syncthreads();
  if (t == 0) {
    const float s = red[0] + red[1] + red[2] + red[3];
    if (row < NROW) rnorm[row] = s; else cnorm[row - NROW] = s;
  }
}

// ipTh[512,2048] = fp16(ip[2048,512]^T)   (feeds the Rt MFMA GEMM)
__global__ __launch_bounds__(256) void ip_t16(
    const float* __restrict__ ip, _Float16* __restrict__ ipTh)
{
  __shared__ float T[64][65];
  const int j0 = blockIdx.x * 64;   // ip row range (0..2047)
  const int f0 = blockIdx.y * 64;   // ip col range (0..511)
  const int t = threadIdx.x;
  #pragma unroll
  for (int l = 0; l < 16; ++l) {
    const int idx = t + l * 256;
    T[idx >> 6][idx & 63] = ip[(size_t)(j0 + (idx >> 6)) * NF + f0 + (idx & 63)];
  }
  __syncthreads();
  #pragma unroll
  for (int l = 0; l < 16; ++l) {
    const int idx = t + l * 256;
    const int fr = idx >> 6, jc = idx & 63;
    ipTh[(size_t)(f0 + fr) * MIND + j0 + jc] = (_Float16)T[jc][fr];
  }
}

// ------------------------------------------------- 256x256 deep-pipe GEMM --
// S = A[M,K] * B[N,K]^T, fp16 K-contiguous, fp32 accumulate.
// 512 threads = 8 waves (2M x 4N), per-wave 128x64 output, BK=32.
// 4 LDS buffers; counted vmcnt(8) keeps 2 tiles in flight across barriers.
// LDS XOR slot-swizzle via pre-swizzled global src (SQ_LDS_BANK_CONFLICT==0).
// XCD-aware block swizzle (T1): same-bm blocks contiguous on one XCD.
//
// PASS 0: A' = [Zh ; Zih] (M = 18432, K = 512), B = Zih, grid (8, 72).
//   bm < 64 : DKout = fp16(exp(-|rn_i + cn_j - 2S|) - CC)       [Kx gen]
//   bm >= 64: Cf = exp(-|rn_i + cn_j - 2S|) + 0.05*(i==j)       [Kreg fp32]
// PASS 1: A = DK (M = 16384, K = 2048), B' = [Kih ; Rt], grid (10, 64).
//   bn < 8  : varacc_i += sum_j (S_ij + CC*u_j) * (CC + DK_ij)  [t o Kx]
//   bn >= 8 : Cf = ((S_ij + CC*colsumR_j)*stdv_j + meanv_j)*mask_i  [x_new]
// PASS 2: A = ipTh (M = 512, K = 2048), B = Kih, grid (8, 2).
//   Rt = fp16(ip^T * Kinv)  [uses Kinv symmetry: Kih rows = Kinv columns;
//   replaces the fp32-VALU gemm_f32 + transpose_colsum pair]
template <int PASS>
__global__ __launch_bounds__(512, 2) void mfma_gemm256f(
    const _Float16* __restrict__ A, const _Float16* __restrict__ B, int K,
    const float* __restrict__ rn, const float* __restrict__ cn,
    _Float16* __restrict__ DKout, float* __restrict__ Cf,
    const _Float16* __restrict__ DK, const float* __restrict__ u,
    float* __restrict__ varacc,
    const float* __restrict__ colsumR, const float* __restrict__ stdv,
    const float* __restrict__ meanv, const int* __restrict__ mask)
{
  __shared__ __align__(16) _Float16 Asmem[4][256 * 32];
  __shared__ __align__(16) _Float16 Bsmem[4][256 * 32];

  const int tid = threadIdx.x;
  const int w = tid >> 6, L = tid & 63;
  const int wm = w >> 2, wn = w & 3;          // 2 x 4 waves
  const int lq = L >> 4, lr = L & 15;
  // ---- XCD-aware remap (T1): same-bm blocks contiguous on one XCD ----
  int bn, bm;
  if constexpr (PASS == 0) {
    const int wgid = blockIdx.y * 8 + blockIdx.x;    // grid (8,72)
    const int xcd = wgid & 7, q = wgid >> 3;         // q: 0..71
    bm = xcd + 8 * (q >> 3);                         // 0..71, bijective
    bn = q & 7;                                      // 0..7
  } else if constexpr (PASS == 1) {
    const int wgid = blockIdx.y * 10 + blockIdx.x;   // grid (10,64)
    const int xcd = wgid & 7, q = wgid >> 3;         // q: 0..79
    bm = xcd + 8 * (q / 10);                         // 0..63, bijective
    bn = q % 10;                                     // 0..9
  } else {
    const int wgid = blockIdx.y * 8 + blockIdx.x;    // grid (8,2): 16 blocks
    bm = wgid >> 3;                                  // 0..1
    bn = wgid & 7;                                   // 0..7 (one bn per XCD)
  }
  const int NT = K >> 5;                      // K tiles of 32

  // ---- staging maps (linear LDS dest = base + lane*16; swizzled global src)
  const int srow  = tid >> 2;                 // 0..127 (chunk j adds 128)
  const int sslot = tid & 3;                  // LDS 16B slot within 64B row
  const int gslot = sslot ^ ((tid >> 3) & 3); // swizzled source slot
  const _Float16* Ag = A + (size_t)(bm * 256 + srow) * K + gslot * 8;
  const _Float16* Bg = B + (size_t)(bn * 256 + srow) * K + gslot * 8;
  const size_t rstride = (size_t)128 * K;
  const int ldst = srow * 32 + sslot * 8;     // halves

  // ---- fragment read offsets (swizzled): slot = lq ^ ((lr>>1)&3)
  const int fswz = (lq ^ ((lr >> 1) & 3)) * 8;
  const int aoff = (wm * 128 + lr) * 32 + fswz;
  const int boff = (wn * 64  + lr) * 32 + fswz;

  floatx4 acc[8][4] = {};

  auto stageA = [&](int t) {
    _Float16* dst = Asmem[t & 3] + ldst;
    const _Float16* src = Ag + (size_t)t * 32;
    gload16(src, dst);
    gload16(src + rstride, dst + 128 * 32);
  };
  auto stageB = [&](int t) {
    _Float16* dst = Bsmem[t & 3] + ldst;
    const _Float16* src = Bg + (size_t)t * 32;
    gload16(src, dst);
    gload16(src + rstride, dst + 128 * 32);
  };

  // ---- prologue: stage tiles 0,1,2 (12 loads); gate tile 0 with vmcnt(8)
  stageA(0); stageB(0);
  if (NT > 1) { stageA(1); stageB(1); }
  if (NT > 2) { stageA(2); stageB(2); }
  if (NT > 2)      { GATE(8); }
  else if (NT > 1) { GATE(4); }
  else             { GATE(0); }
  __builtin_amdgcn_s_barrier();
  MEMFENCE;

  for (int t = 0; t < NT; ++t) {
    const _Float16* As = Asmem[t & 3];
    const _Float16* Bs = Bsmem[t & 3];
    half8 af[4], bf[4], af2[4];

    // ---- phase 0: quadrant mi0-3 --------------------------------------
    #pragma unroll
    for (int mi = 0; mi < 4; ++mi) af[mi] = *(const half8*)&As[aoff + mi * 512];
    #pragma unroll
    for (int ni = 0; ni < 4; ++ni) bf[ni] = *(const half8*)&Bs[boff + ni * 512];
    if (t + 3 < NT) stageA(t + 3);
    MEMFENCE;
    __builtin_amdgcn_s_barrier();
    MEMFENCE;
    __builtin_amdgcn_s_setprio(1);
    #pragma unroll
    for (int mi = 0; mi < 4; ++mi)
      #pragma unroll
      for (int ni = 0; ni < 4; ++ni)
        acc[mi][ni] = __builtin_amdgcn_mfma_f32_16x16x32_f16(
            af[mi], bf[ni], acc[mi][ni], 0, 0, 0);
    __builtin_amdgcn_s_setprio(0);

    // ---- phase 1: quadrant mi4-7 + counted-vmcnt gate for tile t+1 ----
    #pragma unroll
    for (int mi = 0; mi < 4; ++mi)
      af2[mi] = *(const half8*)&As[aoff + (mi + 4) * 512];
    if (t + 3 < NT) stageB(t + 3);
    // outstanding after this phase's stages: tiles {t+2 .. min(t+3,NT-1)}
    if (t + 4 <= NT)      { GATE(8); }   // 2 future tiles in flight
    else if (t + 3 == NT) { GATE(4); }   // 1 future tile
    else if (t + 2 == NT) { GATE(0); }   // drain before last tile
    __builtin_amdgcn_s_barrier();
    MEMFENCE;
    __builtin_amdgcn_s_setprio(1);
    #pragma unroll
    for (int mi = 0; mi < 4; ++mi)
      #pragma unroll
      for (int ni = 0; ni < 4; ++ni)
        acc[mi + 4][ni] = __builtin_amdgcn_mfma_f32_16x16x32_f16(
            af2[mi], bf[ni], acc[mi + 4][ni], 0, 0, 0);
    __builtin_amdgcn_s_setprio(0);
  }

  // ---- epilogue.  C/D layout: col = lane&15, row = (lane>>4)*4 + reg
  const int grb = bm * 256 + wm * 128;
  const int gcb = bn * 256 + wn * 64;

  if constexpr (PASS == 0) {
    if (bm < NROW / 256) {             // EPI0: Kx -> DK fp16
      #pragma unroll
      for (int mi = 0; mi < 8; ++mi)
        #pragma unroll
        for (int e = 0; e < 4; ++e) {
          const int gr = grb + mi * 16 + lq * 4 + e;
          const float rni = rn[gr];
          #pragma unroll
          for (int ni = 0; ni < 4; ++ni) {
            const int gc = gcb + ni * 16 + lr;
            const float d = rni + cn[gc] - 2.f * acc[mi][ni][e];
            DKout[(size_t)gr * MIND + gc] = (_Float16)(expf(-fabsf(d)) - CC);
          }
        }
    } else {                           // EPI1: Kreg fp32 (+0.05 I)
      #pragma unroll
      for (int mi = 0; mi < 8; ++mi)
        #pragma unroll
        for (int e = 0; e < 4; ++e) {
          const int gr = grb + mi * 16 + lq * 4 + e;
          const int gr2 = gr - NROW;
          const float rni = rn[gr];    // rn = rnorm||cnorm contiguous
          #pragma unroll
          for (int ni = 0; ni < 4; ++ni) {
            const int gc = gcb + ni * 16 + lr;
            const float d = rni + cn[gc] - 2.f * acc[mi][ni][e];
            float kx = expf(-fabsf(d));
            if (gr2 == gc) kx += 0.05f;
            Cf[(size_t)gr2 * MIND + gc] = kx;
          }
        }
    }
  } else if constexpr (PASS == 1) {
    if (bn < MIND / 256) {             // EPI2: var reduction
      #pragma unroll
      for (int mi = 0; mi < 8; ++mi)
        #pragma unroll
        for (int e = 0; e < 4; ++e) {
          const int gr = grb + mi * 16 + lq * 4 + e;
          float partial = 0.f;
          #pragma unroll
          for (int ni = 0; ni < 4; ++ni) {
            const int gc = gcb + ni * 16 + lr;
            const float tv = acc[mi][ni][e] + CC * u[gc];
            partial += tv * (CC + (float)DK[(size_t)gr * MIND + gc]);
          }
          partial += __shfl_xor(partial, 1);
          partial += __shfl_xor(partial, 2);
          partial += __shfl_xor(partial, 4);
          partial += __shfl_xor(partial, 8);
          if (lr == 0) atomicAdd(&varacc[gr], partial);
        }
    } else {                           // EPI3: x_new
      const int gcb3 = (bn - MIND / 256) * 256 + wn * 64;
      #pragma unroll
      for (int mi = 0; mi < 8; ++mi)
        #pragma unroll
        for (int e = 0; e < 4; ++e) {
          const int gr = grb + mi * 16 + lq * 4 + e;
          const float mrow = (mask[gr] != 0) ? 1.f : 0.f;
          #pragma unroll
          for (int ni = 0; ni < 4; ++ni) {
            const int gc3 = gcb3 + ni * 16 + lr;
            const float v = acc[mi][ni][e] + CC * colsumR[gc3];
            Cf[(size_t)gr * NF + gc3] = (v * stdv[gc3] + meanv[gc3]) * mrow;
          }
        }
    }
  } else {                             // PASS 2: Rt = fp16(ip^T * Kinv)
    #pragma unroll
    for (int mi = 0; mi < 8; ++mi)
      #pragma unroll
      for (int e = 0; e < 4; ++e) {
        const int gr = grb + mi * 16 + lq * 4 + e;
        #pragma unroll
        for (int ni = 0; ni < 4; ++ni) {
          const int gc = gcb + ni * 16 + lr;
          DKout[(size_t)gr * MIND + gc] = (_Float16)acc[mi][ni][e];
        }
      }
  }
}

// ------------------------------------------------- blocked Gauss-Jordan ----
// Round-1/5 proven version (0-for-5 on restructurings — do not touch).
// 2 launches/iter.  Per iter k (o = 64k):
//   gj_apply: row A_oj = P*Bsave_j; col A_io = -CP_i; big A_ij -= CP_i*Bsave_j;
//             block (o+64,o+64) also runs the 64-step pivot loop -> Pall[k+1]
//   gj_prep:  CP_i = A[i][o']*P';  Bsave = copy of row panel A[o'][:]
// Bootstrap: gj_diag computes Pall[0] from A_00.

__global__ __launch_bounds__(256) void gj_diag(
    float* __restrict__ A, float* __restrict__ Pall, int k)
{
  const int o = k * 64;
  __shared__ float D[64][68];
  const int t = threadIdx.x;
  #pragma unroll
  for (int l = 0; l < 4; ++l) {
    const int v = t + l * 256;
    const int r = v >> 4, c4 = (v & 15) << 2;
    *(float4*)&D[r][c4] = *(const float4*)(A + (size_t)(o + r) * MIND + o + c4);
  }
  __syncthreads();
  const int i = t >> 2, c0 = (t & 3) * 16;
  for (int s = 0; s < 64; ++s) {
    const float p = 1.0f / D[s][s];
    if (t < 64 && t != s) D[s][t] *= p;
    __syncthreads();
    if (i != s) {
      const float f = D[i][s];
      #pragma unroll
      for (int c = c0; c < c0 + 16; c += 4) {
        float4 ds = *(const float4*)&D[s][c];
        float4 di = *(const float4*)&D[i][c];
        di.x -= f * ds.x; di.y -= f * ds.y; di.z -= f * ds.z; di.w -= f * ds.w;
        *(float4*)&D[i][c] = di;
      }
      if (s >= c0 && s < c0 + 16) D[i][s] = -f * p;
    }
    if (t == 0) D[s][s] = p;
    __syncthreads();
  }
  float* P = Pall + k * 4096;
  #pragma unroll
  for (int l = 0; l < 4; ++l) {
    const int v = t + l * 256;
    const int r = v >> 4, c4 = (v & 15) << 2;
    const float4 dv = *(const float4*)&D[r][c4];
    *(float4*)(P + r * 64 + c4) = dv;
    *(float4*)(A + (size_t)(o + r) * MIND + o + c4) = dv;
  }
}

// 64 blocks: bx<32 -> CP_i = A[i][o]*P (skip i==o); bx>=32 -> Bsave row copy
__global__ __launch_bounds__(256) void gj_prep(
    const float* __restrict__ A, const float* __restrict__ Pall,
    float* __restrict__ CP, float* __restrict__ Bsave, int k)
{
  const int o = k * 64;
  const int t = threadIdx.x;
  if (blockIdx.x >= 32) {
    const int j0 = (blockIdx.x - 32) * 64;
    #pragma unroll
    for (int l = 0; l < 4; ++l) {
      const int v = t + l * 256;
      const int r = v >> 4, c4 = (v & 15) << 2;
      *(float4*)(Bsave + r * MIND + j0 + c4) =
          *(const float4*)(A + (size_t)(o + r) * MIND + j0 + c4);
    }
    return;
  }
  const int i0 = blockIdx.x * 64;
  if (i0 == o) return;
  const float* P = Pall + k * 4096;
  __shared__ float At[64][68];   // At[s][r] = A[i0+r][o+s]
  __shared__ float Pl[64][68];   // Pl[s][c] = P[s][c]
  #pragma unroll
  for (int l = 0; l < 4; ++l) {
    const int v = t + l * 256;
    const int r = v >> 4, c4 = (v & 15) << 2;
    const float4 av = *(const float4*)(A + (size_t)(i0 + r) * MIND + o + c4);
    At[c4 + 0][r] = av.x; At[c4 + 1][r] = av.y;
    At[c4 + 2][r] = av.z; At[c4 + 3][r] = av.w;
    *(float4*)&Pl[r][c4] = *(const float4*)(P + r * 64 + c4);
  }
  __syncthreads();
  const int ty = t >> 4, tx = t & 15;
  float acc[4][4] = {};
  for (int s = 0; s < 64; ++s) {
    const float4 a4 = *(const float4*)&At[s][ty * 4];
    const float4 b4 = *(const float4*)&Pl[s][tx * 4];
    const float a[4] = {a4.x, a4.y, a4.z, a4.w};
    const float b[4] = {b4.x, b4.y, b4.z, b4.w};
    #pragma unroll
    for (int i = 0; i < 4; ++i)
      #pragma unroll
      for (int j = 0; j < 4; ++j) acc[i][j] += a[i] * b[j];
  }
  #pragma unroll
  for (int i = 0; i < 4; ++i) {
    float4 o4; o4.x = acc[i][0]; o4.y = acc[i][1]; o4.z = acc[i][2]; o4.w = acc[i][3];
    *(float4*)(CP + (i0 + ty * 4 + i) * 64 + tx * 4) = o4;
  }
}

__global__ __launch_bounds__(256) void gj_apply(
    float* __restrict__ A, float* __restrict__ Pall,
    const float* __restrict__ CP, const float* __restrict__ Bsave, int k)
{
  const int o = k * 64;
  const int i0 = blockIdx.y * 64, j0 = blockIdx.x * 64;
  const int t = threadIdx.x;

  if (i0 == o && j0 == o) return;

  if (j0 == o) {                       // col: A_io = -CP_i (negated copy)
    #pragma unroll
    for (int l = 0; l < 4; ++l) {
      const int v = t + l * 256;
      const int r = v >> 4, c4 = (v & 15) << 2;
      float4 x = *(const float4*)(CP + (i0 + r) * 64 + c4);
      x.x = -x.x; x.y = -x.y; x.z = -x.z; x.w = -x.w;
      *(float4*)(A + (size_t)(i0 + r) * MIND + o + c4) = x;
    }
    return;
  }

  __shared__ float S1[64 * 68];   // Lt (transposed left op); later D for diag
  __shared__ float S2[64 * 68];   // Bsave tile
  #define DD(r, c) S1[(r) * 68 + (c)]

  const bool isrow = (i0 == o);
  const float* Lsrc = isrow ? (Pall + k * 4096) : (CP + i0 * 64);
  #pragma unroll
  for (int l = 0; l < 4; ++l) {
    const int v = t + l * 256;
    const int r = v >> 4, c4 = (v & 15) << 2;
    const float4 lv = *(const float4*)(Lsrc + r * 64 + c4);
    S1[(c4 + 0) * 68 + r] = lv.x; S1[(c4 + 1) * 68 + r] = lv.y;
    S1[(c4 + 2) * 68 + r] = lv.z; S1[(c4 + 3) * 68 + r] = lv.w;
    *(float4*)&S2[r * 68 + c4] = *(const float4*)(Bsave + r * MIND + j0 + c4);
  }
  __syncthreads();
  const int ty = t >> 4, tx = t & 15;
  float acc[4][4] = {};
  for (int s = 0; s < 64; ++s) {
    const float4 a4 = *(const float4*)&S1[s * 68 + ty * 4];
    const float4 b4 = *(const float4*)&S2[s * 68 + tx * 4];
    const float a[4] = {a4.x, a4.y, a4.z, a4.w};
    const float b[4] = {b4.x, b4.y, b4.z, b4.w};
    #pragma unroll
    for (int i = 0; i < 4; ++i)
      #pragma unroll
      for (int j = 0; j < 4; ++j) acc[i][j] += a[i] * b[j];
  }

  if (isrow) {                         // A_oj = P * Bsave_j
    #pragma unroll
    for (int i = 0; i < 4; ++i) {
      float4 o4; o4.x = acc[i][0]; o4.y = acc[i][1]; o4.z = acc[i][2]; o4.w = acc[i][3];
      *(float4*)(A + (size_t)(o + ty * 4 + i) * MIND + j0 + tx * 4) = o4;
    }
    return;
  }

  const bool isdiagnext = (i0 == o + 64) && (j0 == o + 64);
  if (!isdiagnext) {                   // big: A_ij -= CP_i * Bsave_j
    #pragma unroll
    for (int i = 0; i < 4; ++i) {
      float* cp = A + (size_t)(i0 + ty * 4 + i) * MIND + j0 + tx * 4;
      float4 cv = *(const float4*)cp;
      cv.x -= acc[i][0]; cv.y -= acc[i][1]; cv.z -= acc[i][2]; cv.w -= acc[i][3];
      *(float4*)cp = cv;
    }
    return;
  }

  // diag-next: update into LDS, run 64-step pivot loop, emit Pall[k+1] + A
  __syncthreads();                     // S1 readers done
  #pragma unroll
  for (int i = 0; i < 4; ++i) {
    const float4 cv = *(const float4*)(A + (size_t)(i0 + ty * 4 + i) * MIND + j0 + tx * 4);
    DD(ty * 4 + i, tx * 4 + 0) = cv.x - acc[i][0];
    DD(ty * 4 + i, tx * 4 + 1) = cv.y - acc[i][1];
    DD(ty * 4 + i, tx * 4 + 2) = cv.z - acc[i][2];
    DD(ty * 4 + i, tx * 4 + 3) = cv.w - acc[i][3];
  }
  __syncthreads();
  const int di = t >> 2, c0 = (t & 3) * 16;
  for (int s = 0; s < 64; ++s) {
    const float p = 1.0f / DD(s, s);
    if (t < 64 && t != s) DD(s, t) *= p;
    __syncthreads();
    if (di != s) {
      const float f = DD(di, s);
      #pragma unroll
      for (int c = c0; c < c0 + 16; c += 4) {
        float4 ds = *(const float4*)&DD(s, c);
        float4 dv = *(const float4*)&DD(di, c);
        dv.x -= f * ds.x; dv.y -= f * ds.y; dv.z -= f * ds.z; dv.w -= f * ds.w;
        *(float4*)&DD(di, c) = dv;
      }
      if (s >= c0 && s < c0 + 16) DD(di, s) = -f * p;
    }
    if (t == 0) DD(s, s) = p;
    __syncthreads();
  }
  float* Pn = Pall + (k + 1) * 4096;
  #pragma unroll
  for (int l = 0; l < 4; ++l) {
    const int v = t + l * 256;
    const int r = v >> 4, c4 = (v & 15) << 2;
    const float4 dv = *(const float4*)&DD(r, c4);
    *(float4*)(Pn + r * 64 + c4) = dv;
    *(float4*)(A + (size_t)(i0 + r) * MIND + j0 + c4) = dv;
  }
  #undef DD
}

// ----------------------------------------------------------- helpers -------
// u = rowsum(Ai) AND Kih = fp16(Ai) in one pass (one 16.8 MB read, not two)
__global__ __launch_bounds__(256) void rowsum_cast(
    const float* __restrict__ Ai, float* __restrict__ u,
    _Float16* __restrict__ Kih)
{
  const int row = blockIdx.x * 4 + (threadIdx.x >> 6);
  const int lane = threadIdx.x & 63;
  const float* src = Ai + (size_t)row * MIND;
  _Float16* dst = Kih + (size_t)row * MIND;
  float s = 0.f;
  #pragma unroll
  for (int it = 0; it < 8; ++it) {
    const int c = it * 256 + lane * 4;
    const float4 v = *(const float4*)(src + c);
    s += v.x + v.y + v.z + v.w;
    half4v h; h.x = (_Float16)v.x; h.y = (_Float16)v.y;
    h.z = (_Float16)v.z; h.w = (_Float16)v.w;
    *(half4v*)(dst + c) = h;
  }
  #pragma unroll
  for (int off = 32; off; off >>= 1) s += __shfl_xor(s, off);
  if (lane == 0) u[row] = s;
}

// colsumR = ip^T * u  (Kinv symmetric => colsum(Kinv) = rowsum(Kinv) = u,
// so colsum(Kinv*ip) = ip^T * u).  Pure fp32 — more accurate than before.
__global__ __launch_bounds__(256) void colsum_u(
    const float* __restrict__ ip, const float* __restrict__ u,
    float* __restrict__ cs)
{
  const int b = blockIdx.x;
  const int t = threadIdx.x;
  float s0 = 0.f, s1 = 0.f;
  for (int r = 0; r < 64; ++r) {
    const int row = b * 64 + r;
    const float uk = u[row];
    s0 += uk * ip[(size_t)row * NF + t];
    s1 += uk * ip[(size_t)row * NF + t + 256];
  }
  atomicAdd(&cs[t], s0); atomicAdd(&cs[t + 256], s1);
}

__global__ __launch_bounds__(256) void var_finalize(
    const float* __restrict__ varacc, const int* __restrict__ mask,
    float* __restrict__ outv)
{
  const int i = blockIdx.x * 256 + threadIdx.x;
  const float m = (mask[i] != 0) ? 1.f : 0.f;
  outv[i] = (1.0f - varacc[i]) * m;
}

}  // namespace

extern "C" void kernel_launch(void* const* d_in, const int* in_sizes, int n_in,
                              void* d_out, int out_size, void* d_ws, size_t ws_size,
                              hipStream_t stream)
{
  (void)in_sizes; (void)n_in; (void)out_size; (void)ws_size;
  const float* x     = (const float*)d_in[0];
  const int*   mask  = (const int*)d_in[1];
  const float* ip    = (const float*)d_in[2];
  const float* gamma = (const float*)d_in[3];
  float* out = (float*)d_out;

  float* w       = (float*)d_ws;
  float* sum     = w;                     // 512
  float* sumsq   = w + 512;               // 512
  float* cnt     = w + 1024;              // 1 (padded 512)
  float* varacc  = w + 1536;              // 16384
  float* colsumR = w + 17920;             // 512   -> [0, 18432) zeroed
  float* meanv   = w + 18432;
  float* stdv    = w + 18944;
  float* zsv     = w + 19456;
  float* giv     = w + 19968;
  float* rnorm   = w + 20480;             // 16384  } rnorm||cnorm contiguous
  float* cnorm   = w + 36864;             // 2048   }
  float* u       = w + 38912;             // 2048
  float* Ai      = w + 40960;             // 2048*2048 (Kreg -> Kinv in place)
  _Float16* ipTh = (_Float16*)(w + 4235264);  // 512*2048 fp16 (old R slot)
  float* Pall    = w + 5283840;           // 32*4096 pivot inverses
  float* CP      = w + 5414912;           // 2048*64
  float* Bsave   = w + 5545984;           // 64*2048
  _Float16* hb   = (_Float16*)(w + 5677056);
  _Float16* Zh   = hb;                    // 16384*512 } Zh||Zih contiguous
  _Float16* Zih  = hb + 8388608;          // 2048*512  }
  _Float16* DK   = hb + 9437184;          // 16384*2048
  _Float16* Kih  = hb + 42991616;         // 2048*2048 } Kih||Rt contiguous
  _Float16* Rt   = hb + 47185920;         // 512*2048  }

  hipMemsetAsync(w, 0, 18432 * sizeof(float), stream);

  stats_kernel<<<256, 256, 0, stream>>>(x, mask, sum, sumsq, cnt);
  finalize_stats<<<2, 256, 0, stream>>>(sum, sumsq, cnt, gamma, meanv, stdv, zsv, giv);
  make_z<<<NROW + MIND, 256, 0, stream>>>(x, mask, ip, meanv, zsv, giv, Zh, Zih, rnorm, cnorm);
  ip_t16<<<dim3(MIND / 64, NF / 64), 256, 0, stream>>>(ip, ipTh);

  // PASS 0: A' = [Zh;Zih] -> DK (bm<64) + Kreg/Ai (bm>=64), XCD-swizzled
  mfma_gemm256f<0><<<dim3(MIND / 256, (NROW + MIND) / 256), 512, 0, stream>>>(
      Zh, Zih, NF, rnorm, cnorm,
      DK, Ai, nullptr, nullptr, nullptr, nullptr, nullptr, nullptr, nullptr);

  // blocked Gauss-Jordan inverse, 2 launches/iter, diag hidden in apply
  gj_diag<<<1, 256, 0, stream>>>(Ai, Pall, 0);
  gj_prep<<<64, 256, 0, stream>>>(Ai, Pall, CP, Bsave, 0);
  for (int k = 0; k < 32; ++k) {
    gj_apply<<<dim3(32, 32), 256, 0, stream>>>(Ai, Pall, CP, Bsave, k);
    if (k < 31) gj_prep<<<64, 256, 0, stream>>>(Ai, Pall, CP, Bsave, k + 1);
  }

  // u + Kih (one Ai pass); Rt = fp16(ip^T * Kinv) on the MFMA pipeline
  // (Kinv symmetry); colsumR = ip^T * u (fp32 GEMV)
  rowsum_cast<<<MIND / 4, 256, 0, stream>>>(Ai, u, Kih);
  mfma_gemm256f<2><<<dim3(8, 2), 512, 0, stream>>>(
      ipTh, Kih, MIND, nullptr, nullptr,
      Rt, nullptr, nullptr, nullptr, nullptr, nullptr, nullptr, nullptr, nullptr);
  colsum_u<<<MIND / 64, 256, 0, stream>>>(ip, u, colsumR);

  // PASS 1: B' = [Kih;Rt] -> varacc (bn<8) + x_new (bn>=8), XCD-swizzled;
  // DK A-panels staged once for both outputs
  mfma_gemm256f<1><<<dim3((MIND + NF) / 256, NROW / 256), 512, 0, stream>>>(
      DK, Kih, MIND, nullptr, nullptr,
      nullptr, out, DK, u, varacc, colsumR, stdv, meanv, mask);

  var_finalize<<<NROW / 256, 256, 0, stream>>>(varacc, mask, out + (size_t)NROW * NF);
}